// Round 2
// baseline (4744.823 us; speedup 1.0000x reference)
//
#include <hip/hip_runtime.h>
#include <math.h>

static constexpr int F_IN = 78, H1 = 10, F1c = 78, C1 = 780, F2 = 128, EMB = 320;

__device__ __forceinline__ unsigned enc_f(float f) {
    unsigned u = __float_as_uint(f);
    return (u & 0x80000000u) ? ~u : (u | 0x80000000u);
}
__device__ __forceinline__ float dec_f(unsigned u) {
    return (u & 0x80000000u) ? __uint_as_float(u ^ 0x80000000u) : __uint_as_float(~u);
}

// h1h[n,c] = sum_k x[n,k] * W1[k, hb+c]   (W1 row-major 78x780)
__global__ void k_gemm1h(const float* __restrict__ x, const float* __restrict__ W1, int hb,
                         float* __restrict__ h1h, int N) {
    int idx = blockIdx.x * 256 + threadIdx.x;
    if (idx >= N * F1c) return;
    int n = idx / F1c, c = idx - n * F1c;
    const float* xr = x + (size_t)n * F_IN;
    const float* wp = W1 + hb + c;
    float acc = 0.f;
#pragma unroll
    for (int k = 0; k < F_IN; k++) acc = fmaf(xr[k], wp[k * C1], acc);
    h1h[idx] = acc;
}

// es[n] = sum_f h[n,f]*as[f]; ed[n] = sum_f h[n,f]*ad[f]
__global__ void k_coef(const float* __restrict__ h, const float* __restrict__ as,
                       const float* __restrict__ ad, float* __restrict__ es,
                       float* __restrict__ ed, int N, int F) {
    int n = blockIdx.x * 256 + threadIdx.x;
    if (n >= N) return;
    const float* hp = h + (size_t)n * F;
    float s = 0.f, d = 0.f;
    for (int f = 0; f < F; f++) {
        float v = hp[f];
        s = fmaf(v, as[f], s);
        d = fmaf(v, ad[f], d);
    }
    es[n] = s;
    ed[n] = d;
}

__device__ __forceinline__ void esd(const int* src, const int* dst, int E, int e, int& s, int& d) {
    if (e < E) { s = src[e]; d = dst[e]; }
    else       { s = e - E; d = s; }
}

__global__ void k_edge_max(const int* __restrict__ src, const int* __restrict__ dst, int E,
                           int Etot, const float* __restrict__ es, const float* __restrict__ ed,
                           unsigned* __restrict__ menc) {
    int e = blockIdx.x * 256 + threadIdx.x;
    if (e >= Etot) return;
    int s, d;
    esd(src, dst, E, e, s, d);
    float v = es[s] + ed[d];
    v = v >= 0.f ? v : 0.2f * v;
    atomicMax(&menc[d], enc_f(v));
}

__global__ void k_edge_exp(const int* __restrict__ src, const int* __restrict__ dst, int E,
                           int Etot, const float* __restrict__ es, const float* __restrict__ ed,
                           const unsigned* __restrict__ menc, float* __restrict__ al,
                           float* __restrict__ dn) {
    int e = blockIdx.x * 256 + threadIdx.x;
    if (e >= Etot) return;
    int s, d;
    esd(src, dst, E, e, s, d);
    float v = es[s] + ed[d];
    v = v >= 0.f ? v : 0.2f * v;
    float p = __expf(v - dec_f(menc[d]));
    al[e] = p;
    atomicAdd(&dn[d], p);
}

__global__ void k_edge_div(const int* __restrict__ dst, int E, int Etot,
                           const float* __restrict__ dn, float* __restrict__ al) {
    int e = blockIdx.x * 256 + threadIdx.x;
    if (e >= Etot) return;
    int d = (e < E) ? dst[e] : (e - E);
    al[e] = al[e] / dn[d];
}

template <int F>
__global__ void k_aggr(const int* __restrict__ src, const int* __restrict__ dst, int E, int Etot,
                       const float* __restrict__ al, const float* __restrict__ h,
                       float* __restrict__ out) {
    int idx = blockIdx.x * 256 + threadIdx.x;
    if (idx >= Etot * F) return;
    int e = idx / F, c = idx - e * F;
    int s, d;
    esd(src, dst, E, e, s, d);
    atomicAdd(&out[(size_t)d * F + c], al[e] * h[(size_t)s * F + c]);
}

template <int F>
__global__ void k_bias_elu(float* __restrict__ o, const float* __restrict__ b, int N) {
    int idx = blockIdx.x * 256 + threadIdx.x;
    if (idx >= N * F) return;
    int c = idx % F;
    float v = o[idx] + b[c];
    o[idx] = v > 0.f ? v : expm1f(v);
}

// h2[n,c] += sum_k a[n,k] * W2[hb+k, c]   (a: N x 78 post-elu, W2 row-major 780x128)
__global__ void k_gemm_acc(const float* __restrict__ a, const float* __restrict__ W2, int hb,
                           float* __restrict__ h2, int N) {
    int idx = blockIdx.x * 256 + threadIdx.x;
    if (idx >= N * F2) return;
    int n = idx >> 7, c = idx & 127;
    const float* ar = a + (size_t)n * F1c;
    const float* wp = W2 + (size_t)hb * F2 + c;
    float acc = h2[idx];
#pragma unroll
    for (int k = 0; k < F1c; k++) acc = fmaf(ar[k], wp[k * F2], acc);
    h2[idx] = acc;
}

// relu(o2 + b2) -> per-graph max (bits trick: values >= 0, gb pre-zeroed)
__global__ void k_pool(const float* __restrict__ o, const float* __restrict__ b2,
                       const int* __restrict__ batch, unsigned* __restrict__ gbits, int N) {
    int idx = blockIdx.x * 256 + threadIdx.x;
    if (idx >= N * F2) return;
    int n = idx >> 7, c = idx & 127;
    float v = fmaxf(o[idx] + b2[c], 0.f);
    atomicMax(&gbits[(size_t)batch[n] * F2 + c], __float_as_uint(v));
}

__global__ void k_head_g(const unsigned* __restrict__ gbits, const float* __restrict__ Wg,
                         const float* __restrict__ bg, float* __restrict__ xc) {
    int b = blockIdx.x, c = threadIdx.x;
    __shared__ float srow[F2];
    srow[c] = __uint_as_float(gbits[(size_t)b * F2 + c]);
    __syncthreads();
    float acc = bg[c];
    for (int k = 0; k < F2; k++) acc = fmaf(srow[k], Wg[k * F2 + c], acc);
    xc[(size_t)b * 256 + c] = fmaxf(acc, 0.f);
}

__global__ void k_head_xt(const float* __restrict__ te, const float* __restrict__ Wxt,
                          const float* __restrict__ bxt, const float* __restrict__ gamma,
                          const float* __restrict__ beta, const float* __restrict__ rmean,
                          const float* __restrict__ rvar, float* __restrict__ xc) {
    int b = blockIdx.x, c = threadIdx.x;
    __shared__ float srow[EMB];
    for (int k = c; k < EMB; k += 128) srow[k] = te[(size_t)b * EMB + k];
    __syncthreads();
    float acc = bxt[c];
    for (int k = 0; k < EMB; k++) acc = fmaf(srow[k], Wxt[k * F2 + c], acc);
    acc = (acc - rmean[c]) * rsqrtf(rvar[c] + 1e-5f) * gamma[c] + beta[c];
    xc[(size_t)b * 256 + 128 + c] = fmaxf(acc, 0.f);
}

__global__ void k_head_f1(const float* __restrict__ xc, const float* __restrict__ W,
                          const float* __restrict__ bias, float* __restrict__ o) {
    int b = blockIdx.x;
    __shared__ float srow[256];
    srow[threadIdx.x] = xc[(size_t)b * 256 + threadIdx.x];
    __syncthreads();
    for (int col = threadIdx.x; col < 1024; col += 256) {
        float acc = bias[col];
        for (int k = 0; k < 256; k++) acc = fmaf(srow[k], W[k * 1024 + col], acc);
        o[(size_t)b * 1024 + col] = fmaxf(acc, 0.f);
    }
}

__global__ void k_head_f2(const float* __restrict__ in, const float* __restrict__ W,
                          const float* __restrict__ bias, float* __restrict__ o) {
    int b = blockIdx.x;
    int col = threadIdx.x;
    __shared__ float srow[1024];
    for (int k = col; k < 1024; k += 256) srow[k] = in[(size_t)b * 1024 + k];
    __syncthreads();
    float acc = bias[col];
    for (int k = 0; k < 1024; k++) acc = fmaf(srow[k], W[k * 256 + col], acc);
    o[(size_t)b * 256 + col] = fmaxf(acc, 0.f);
}

__global__ void k_head_out(const float* __restrict__ in, const float* __restrict__ Wo,
                           const float* __restrict__ bo, float* __restrict__ out) {
    int b = blockIdx.x;
    float acc = 0.f;
    for (int k = threadIdx.x; k < 256; k += 64) acc = fmaf(in[(size_t)b * 256 + k], Wo[k], acc);
    for (int off = 32; off; off >>= 1) acc += __shfl_down(acc, off);
    if (threadIdx.x == 0) out[b] = acc + bo[0];
}

extern "C" void kernel_launch(void* const* d_in, const int* in_sizes, int n_in,
                              void* d_out, int out_size, void* d_ws, size_t ws_size,
                              hipStream_t stream) {
    const float* x     = (const float*)d_in[0];
    const int*   ei    = (const int*)d_in[1];
    const int*   batch = (const int*)d_in[2];
    const float* te    = (const float*)d_in[3];
    const float* W1    = (const float*)d_in[4];
    const float* a1s   = (const float*)d_in[5];
    const float* a1d   = (const float*)d_in[6];
    const float* b1    = (const float*)d_in[7];
    const float* W2    = (const float*)d_in[8];
    const float* a2s   = (const float*)d_in[9];
    const float* a2d   = (const float*)d_in[10];
    const float* b2    = (const float*)d_in[11];
    const float* Wg    = (const float*)d_in[12];
    const float* bg    = (const float*)d_in[13];
    const float* Wxt   = (const float*)d_in[14];
    const float* bxt   = (const float*)d_in[15];
    const float* gamma = (const float*)d_in[16];
    const float* beta  = (const float*)d_in[17];
    const float* rmean = (const float*)d_in[18];
    const float* rvar  = (const float*)d_in[19];
    const float* Wf1   = (const float*)d_in[20];
    const float* bf1   = (const float*)d_in[21];
    const float* Wf2   = (const float*)d_in[22];
    const float* bf2   = (const float*)d_in[23];
    const float* Wo    = (const float*)d_in[24];
    const float* bo    = (const float*)d_in[25];

    const int N = in_sizes[0] / F_IN;
    const int E = in_sizes[1] / 2;
    const int B = in_sizes[3] / EMB;
    const int Etot = E + N;
    const int* src = ei;
    const int* dst = ei + E;

    char* p = (char*)d_ws;
    auto alloc = [&](size_t bytes) -> void* {
        void* r = p;
        p += (bytes + 255) & ~(size_t)255;
        return r;
    };
    // ~90 MB total — keeps well inside workspace.
    float*    h1h  = (float*)alloc((size_t)N * F1c * 4);   // 15.6 MB
    float*    aggh = (float*)alloc((size_t)N * F1c * 4);   // 15.6 MB
    float*    es   = (float*)alloc((size_t)N * 4);
    float*    ed   = (float*)alloc((size_t)N * 4);
    unsigned* m    = (unsigned*)alloc((size_t)N * 4);      // m,dn adjacent -> one memset
    float*    dn   = (float*)alloc((size_t)N * 4);
    float*    al   = (float*)alloc((size_t)Etot * 4);      // 1.8 MB
    float*    h2   = (float*)alloc((size_t)N * F2 * 4);    // 25.6 MB
    float*    o2   = (float*)alloc((size_t)N * F2 * 4);    // 25.6 MB
    unsigned* gb   = (unsigned*)alloc((size_t)B * F2 * 4);
    float*    xc   = (float*)alloc((size_t)B * 256 * 4);
    float*    f1o  = (float*)alloc((size_t)B * 1024 * 4);
    float*    f2o  = (float*)alloc((size_t)B * 256 * 4);

    auto gsz = [](long long t) { return (int)((t + 255) / 256); };

    hipMemsetAsync(h2, 0, (size_t)N * F2 * 4, stream);

    // ---- GAT layer 1, head by head ----
    for (int h = 0; h < H1; h++) {
        int hb = h * F1c;
        hipMemsetAsync(m, 0, (size_t)N * 8, stream);  // covers m and dn (adjacent, N*4 each)
        hipMemsetAsync(aggh, 0, (size_t)N * F1c * 4, stream);

        k_gemm1h<<<gsz((long long)N * F1c), 256, 0, stream>>>(x, W1, hb, h1h, N);
        k_coef<<<gsz(N), 256, 0, stream>>>(h1h, a1s + hb, a1d + hb, es, ed, N, F1c);
        k_edge_max<<<gsz(Etot), 256, 0, stream>>>(src, dst, E, Etot, es, ed, m);
        k_edge_exp<<<gsz(Etot), 256, 0, stream>>>(src, dst, E, Etot, es, ed, m, al, dn);
        k_edge_div<<<gsz(Etot), 256, 0, stream>>>(dst, E, Etot, dn, al);
        k_aggr<F1c><<<gsz((long long)Etot * F1c), 256, 0, stream>>>(src, dst, E, Etot, al, h1h, aggh);
        k_bias_elu<F1c><<<gsz((long long)N * F1c), 256, 0, stream>>>(aggh, b1 + hb, N);
        k_gemm_acc<<<gsz((long long)N * F2), 256, 0, stream>>>(aggh, W2, hb, h2, N);
    }

    // ---- GAT layer 2 (heads=1, 128 ch) ----
    hipMemsetAsync(m, 0, (size_t)N * 8, stream);
    hipMemsetAsync(o2, 0, (size_t)N * F2 * 4, stream);
    hipMemsetAsync(gb, 0, (size_t)B * F2 * 4, stream);

    k_coef<<<gsz(N), 256, 0, stream>>>(h2, a2s, a2d, es, ed, N, F2);
    k_edge_max<<<gsz(Etot), 256, 0, stream>>>(src, dst, E, Etot, es, ed, m);
    k_edge_exp<<<gsz(Etot), 256, 0, stream>>>(src, dst, E, Etot, es, ed, m, al, dn);
    k_edge_div<<<gsz(Etot), 256, 0, stream>>>(dst, E, Etot, dn, al);
    k_aggr<F2><<<gsz((long long)Etot * F2), 256, 0, stream>>>(src, dst, E, Etot, al, h2, o2);
    k_pool<<<gsz((long long)N * F2), 256, 0, stream>>>(o2, b2, batch, gb, N);

    // ---- head ----
    k_head_g<<<B, 128, 0, stream>>>(gb, Wg, bg, xc);
    k_head_xt<<<B, 128, 0, stream>>>(te, Wxt, bxt, gamma, beta, rmean, rvar, xc);
    k_head_f1<<<B, 256, 0, stream>>>(xc, Wf1, bf1, f1o);
    k_head_f2<<<B, 256, 0, stream>>>(f1o, Wf2, bf2, f2o);
    k_head_out<<<B, 64, 0, stream>>>(f2o, Wo, bo, (float*)d_out);
}

// Round 3
// 3220.265 us; speedup vs baseline: 1.4734x; 1.4734x over previous
//
#include <hip/hip_runtime.h>
#include <math.h>

static constexpr int F_IN = 78, H1 = 10, F1c = 78, C1 = 780, F2 = 128, EMB = 320;

__device__ __forceinline__ void esd(const int* src, const int* dst, int E, int e, int& s, int& d) {
    if (e < E) { s = src[e]; d = dst[e]; }
    else       { s = e - E; d = s; }
}

// ---------------- CSR build ----------------
__global__ void k_count(const int* __restrict__ src, const int* __restrict__ dst, int E, int Etot,
                        int* __restrict__ cnt) {
    int e = blockIdx.x * 256 + threadIdx.x;
    if (e >= Etot) return;
    int s, d;
    esd(src, dst, E, e, s, d);
    atomicAdd(&cnt[d], 1);
}

__global__ void k_scan1(const int* __restrict__ in, int* __restrict__ out, int* __restrict__ bsum,
                        int n) {
    __shared__ int tmp[256];
    int t = threadIdx.x;
    int gid = blockIdx.x * 256 + t;
    int v = gid < n ? in[gid] : 0;
    tmp[t] = v;
    __syncthreads();
    for (int off = 1; off < 256; off <<= 1) {
        int u = (t >= off) ? tmp[t - off] : 0;
        __syncthreads();
        tmp[t] += u;
        __syncthreads();
    }
    if (gid < n) out[gid] = tmp[t] - v;  // exclusive within block
    if (t == 255) bsum[blockIdx.x] = tmp[255];
}

__global__ void k_scan2(int* __restrict__ bsum, int nb) {
    if (threadIdx.x == 0) {
        int run = 0;
        for (int i = 0; i < nb; i++) { int v = bsum[i]; bsum[i] = run; run += v; }
    }
}

__global__ void k_scan3(int* __restrict__ out, const int* __restrict__ bsum, int n, int Etot,
                        int* __restrict__ rp_last) {
    int gid = blockIdx.x * 256 + threadIdx.x;
    if (gid < n) out[gid] += bsum[blockIdx.x];
    if (gid == 0) rp_last[0] = Etot;
}

__global__ void k_scatter(const int* __restrict__ src, const int* __restrict__ dst, int E, int Etot,
                          int* __restrict__ cur, int* __restrict__ csrc) {
    int e = blockIdx.x * 256 + threadIdx.x;
    if (e >= Etot) return;
    int s, d;
    esd(src, dst, E, e, s, d);
    int pos = atomicAdd(&cur[d], 1);
    csrc[pos] = s;
}

// ---------------- dense pieces ----------------
// h1h[n,c] = sum_k x[n,k] * W1[k, hb+c]
__global__ void k_gemm1h(const float* __restrict__ x, const float* __restrict__ W1, int hb,
                         float* __restrict__ h1h, int N) {
    int idx = blockIdx.x * 256 + threadIdx.x;
    if (idx >= N * F1c) return;
    int n = idx / F1c, c = idx - n * F1c;
    const float* xr = x + (size_t)n * F_IN;
    const float* wp = W1 + hb + c;
    float acc = 0.f;
#pragma unroll
    for (int k = 0; k < F_IN; k++) acc = fmaf(xr[k], wp[k * C1], acc);
    h1h[idx] = acc;
}

__global__ void k_coef(const float* __restrict__ h, const float* __restrict__ as,
                       const float* __restrict__ ad, float* __restrict__ es,
                       float* __restrict__ ed, int N, int F) {
    int n = blockIdx.x * 256 + threadIdx.x;
    if (n >= N) return;
    const float* hp = h + (size_t)n * F;
    float s = 0.f, d = 0.f;
    for (int f = 0; f < F; f++) {
        float v = hp[f];
        s = fmaf(v, as[f], s);
        d = fmaf(v, ad[f], d);
    }
    es[n] = s;
    ed[n] = d;
}

// ---------------- fused per-node GAT (softmax + aggregate + epilogue) ----------------
// one 64-lane wave per node; 4 nodes per 256-thread block
template <int F, bool POOL>
__global__ void k_gat_node(const int* __restrict__ rp, const int* __restrict__ csrc,
                           const float* __restrict__ es, const float* __restrict__ ed,
                           const float* __restrict__ h, const float* __restrict__ bias,
                           float* __restrict__ out, const int* __restrict__ batch,
                           unsigned* __restrict__ gb, int N) {
    int node = blockIdx.x * 4 + (threadIdx.x >> 6);
    if (node >= N) return;
    int lane = threadIdx.x & 63;
    int beg = rp[node], end = rp[node + 1];
    float edn = ed[node];

    // pass A: max over incoming edges (edge-parallel)
    float m = -INFINITY;
    for (int e = beg + lane; e < end; e += 64) {
        int s = csrc[e];
        float v = es[s] + edn;
        v = v >= 0.f ? v : 0.2f * v;
        m = fmaxf(m, v);
    }
    for (int off = 32; off; off >>= 1) m = fmaxf(m, __shfl_xor(m, off));

    // pass B: softmax denominator
    float dsum = 0.f;
    for (int e = beg + lane; e < end; e += 64) {
        int s = csrc[e];
        float v = es[s] + edn;
        v = v >= 0.f ? v : 0.2f * v;
        dsum += expf(v - m);
    }
    for (int off = 32; off; off >>= 1) dsum += __shfl_xor(dsum, off);
    float inv = 1.f / dsum;

    // pass C: aggregate (sequential over edges, channel-parallel)
    float acc0 = 0.f, acc1 = 0.f;
    for (int e = beg; e < end; e++) {
        int s = csrc[e];
        float v = es[s] + edn;
        v = v >= 0.f ? v : 0.2f * v;
        float a = expf(v - m) * inv;
        const float* hp = h + (size_t)s * F;
        acc0 = fmaf(a, hp[lane], acc0);
        if (F > 64 && 64 + lane < F) acc1 = fmaf(a, hp[64 + lane], acc1);
    }

    if (!POOL) {
        float v0 = acc0 + bias[lane];
        out[(size_t)node * F + lane] = v0 > 0.f ? v0 : expm1f(v0);
        if (F > 64 && 64 + lane < F) {
            float v1 = acc1 + bias[64 + lane];
            out[(size_t)node * F + 64 + lane] = v1 > 0.f ? v1 : expm1f(v1);
        }
    } else {
        unsigned* gp = gb + (size_t)batch[node] * F;
        float v0 = fmaxf(acc0 + bias[lane], 0.f);
        atomicMax(&gp[lane], __float_as_uint(v0));
        if (F > 64 && 64 + lane < F) {
            float v1 = fmaxf(acc1 + bias[64 + lane], 0.f);
            atomicMax(&gp[64 + lane], __float_as_uint(v1));
        }
    }
}

// h2[n,c] += sum_k a[n,k] * W2[hb+k, c]
__global__ void k_gemm_acc(const float* __restrict__ a, const float* __restrict__ W2, int hb,
                           float* __restrict__ h2, int N) {
    int idx = blockIdx.x * 256 + threadIdx.x;
    if (idx >= N * F2) return;
    int n = idx >> 7, c = idx & 127;
    const float* ar = a + (size_t)n * F1c;
    const float* wp = W2 + (size_t)hb * F2 + c;
    float acc = h2[idx];
#pragma unroll
    for (int k = 0; k < F1c; k++) acc = fmaf(ar[k], wp[k * F2], acc);
    h2[idx] = acc;
}

// ---------------- head ----------------
__global__ void k_head_g(const unsigned* __restrict__ gbits, const float* __restrict__ Wg,
                         const float* __restrict__ bg, float* __restrict__ xc) {
    int b = blockIdx.x, c = threadIdx.x;
    __shared__ float srow[F2];
    srow[c] = __uint_as_float(gbits[(size_t)b * F2 + c]);
    __syncthreads();
    float acc = bg[c];
    for (int k = 0; k < F2; k++) acc = fmaf(srow[k], Wg[k * F2 + c], acc);
    xc[(size_t)b * 256 + c] = fmaxf(acc, 0.f);
}

__global__ void k_head_xt(const float* __restrict__ te, const float* __restrict__ Wxt,
                          const float* __restrict__ bxt, const float* __restrict__ gamma,
                          const float* __restrict__ beta, const float* __restrict__ rmean,
                          const float* __restrict__ rvar, float* __restrict__ xc) {
    int b = blockIdx.x, c = threadIdx.x;
    __shared__ float srow[EMB];
    for (int k = c; k < EMB; k += 128) srow[k] = te[(size_t)b * EMB + k];
    __syncthreads();
    float acc = bxt[c];
    for (int k = 0; k < EMB; k++) acc = fmaf(srow[k], Wxt[k * F2 + c], acc);
    acc = (acc - rmean[c]) * rsqrtf(rvar[c] + 1e-5f) * gamma[c] + beta[c];
    xc[(size_t)b * 256 + 128 + c] = fmaxf(acc, 0.f);
}

__global__ void k_head_f1(const float* __restrict__ xc, const float* __restrict__ W,
                          const float* __restrict__ bias, float* __restrict__ o) {
    int b = blockIdx.x;
    __shared__ float srow[256];
    srow[threadIdx.x] = xc[(size_t)b * 256 + threadIdx.x];
    __syncthreads();
    for (int col = threadIdx.x; col < 1024; col += 256) {
        float acc = bias[col];
        for (int k = 0; k < 256; k++) acc = fmaf(srow[k], W[k * 1024 + col], acc);
        o[(size_t)b * 1024 + col] = fmaxf(acc, 0.f);
    }
}

__global__ void k_head_f2(const float* __restrict__ in, const float* __restrict__ W,
                          const float* __restrict__ bias, float* __restrict__ o) {
    int b = blockIdx.x;
    int col = threadIdx.x;
    __shared__ float srow[1024];
    for (int k = col; k < 1024; k += 256) srow[k] = in[(size_t)b * 1024 + k];
    __syncthreads();
    float acc = bias[col];
    for (int k = 0; k < 1024; k++) acc = fmaf(srow[k], W[k * 256 + col], acc);
    o[(size_t)b * 256 + col] = fmaxf(acc, 0.f);
}

__global__ void k_head_out(const float* __restrict__ in, const float* __restrict__ Wo,
                           const float* __restrict__ bo, float* __restrict__ out) {
    int b = blockIdx.x;
    float acc = 0.f;
    for (int k = threadIdx.x; k < 256; k += 64) acc = fmaf(in[(size_t)b * 256 + k], Wo[k], acc);
    for (int off = 32; off; off >>= 1) acc += __shfl_down(acc, off);
    if (threadIdx.x == 0) out[b] = acc + bo[0];
}

extern "C" void kernel_launch(void* const* d_in, const int* in_sizes, int n_in,
                              void* d_out, int out_size, void* d_ws, size_t ws_size,
                              hipStream_t stream) {
    const float* x     = (const float*)d_in[0];
    const int*   ei    = (const int*)d_in[1];
    const int*   batch = (const int*)d_in[2];
    const float* te    = (const float*)d_in[3];
    const float* W1    = (const float*)d_in[4];
    const float* a1s   = (const float*)d_in[5];
    const float* a1d   = (const float*)d_in[6];
    const float* b1    = (const float*)d_in[7];
    const float* W2    = (const float*)d_in[8];
    const float* a2s   = (const float*)d_in[9];
    const float* a2d   = (const float*)d_in[10];
    const float* b2    = (const float*)d_in[11];
    const float* Wg    = (const float*)d_in[12];
    const float* bg    = (const float*)d_in[13];
    const float* Wxt   = (const float*)d_in[14];
    const float* bxt   = (const float*)d_in[15];
    const float* gamma = (const float*)d_in[16];
    const float* beta  = (const float*)d_in[17];
    const float* rmean = (const float*)d_in[18];
    const float* rvar  = (const float*)d_in[19];
    const float* Wf1   = (const float*)d_in[20];
    const float* bf1   = (const float*)d_in[21];
    const float* Wf2   = (const float*)d_in[22];
    const float* bf2   = (const float*)d_in[23];
    const float* Wo    = (const float*)d_in[24];
    const float* bo    = (const float*)d_in[25];

    const int N = in_sizes[0] / F_IN;
    const int E = in_sizes[1] / 2;
    const int B = in_sizes[3] / EMB;
    const int Etot = E + N;
    const int* src = ei;
    const int* dst = ei + E;

    char* p = (char*)d_ws;
    auto alloc = [&](size_t bytes) -> void* {
        void* r = p;
        p += (bytes + 255) & ~(size_t)255;
        return r;
    };
    float*    h1h  = (float*)alloc((size_t)N * F1c * 4);
    float*    aggh = (float*)alloc((size_t)N * F1c * 4);
    float*    es   = (float*)alloc((size_t)N * 4);
    float*    ed   = (float*)alloc((size_t)N * 4);
    float*    h2   = (float*)alloc((size_t)N * F2 * 4);
    int*      cnt  = (int*)alloc((size_t)N * 4);
    int*      rp   = (int*)alloc((size_t)(N + 1) * 4);
    int*      cur  = (int*)alloc((size_t)N * 4);
    int*      csrc = (int*)alloc((size_t)Etot * 4);
    int*      bsum = (int*)alloc((size_t)1024 * 4);
    unsigned* gb   = (unsigned*)alloc((size_t)B * F2 * 4);
    float*    xc   = (float*)alloc((size_t)B * 256 * 4);
    float*    f1o  = (float*)alloc((size_t)B * 1024 * 4);
    float*    f2o  = (float*)alloc((size_t)B * 256 * 4);

    auto gsz = [](long long t) { return (int)((t + 255) / 256); };
    const int nb = gsz(N);

    // ---- CSR build (dst-sorted incoming edge lists, self-loops appended) ----
    hipMemsetAsync(cnt, 0, (size_t)N * 4, stream);
    k_count<<<gsz(Etot), 256, 0, stream>>>(src, dst, E, Etot, cnt);
    k_scan1<<<nb, 256, 0, stream>>>(cnt, rp, bsum, N);
    k_scan2<<<1, 64, 0, stream>>>(bsum, nb);
    k_scan3<<<nb, 256, 0, stream>>>(rp, bsum, N, Etot, rp + N);
    hipMemcpyAsync(cur, rp, (size_t)N * 4, hipMemcpyDeviceToDevice, stream);
    k_scatter<<<gsz(Etot), 256, 0, stream>>>(src, dst, E, Etot, cur, csrc);

    hipMemsetAsync(h2, 0, (size_t)N * F2 * 4, stream);
    hipMemsetAsync(gb, 0, (size_t)B * F2 * 4, stream);

    // ---- GAT layer 1, head by head ----
    for (int h = 0; h < H1; h++) {
        int hb = h * F1c;
        k_gemm1h<<<gsz((long long)N * F1c), 256, 0, stream>>>(x, W1, hb, h1h, N);
        k_coef<<<nb, 256, 0, stream>>>(h1h, a1s + hb, a1d + hb, es, ed, N, F1c);
        k_gat_node<F1c, false><<<gsz((long long)N) * 64, 256, 0, stream>>>(
            rp, csrc, es, ed, h1h, b1 + hb, aggh, nullptr, nullptr, N);
        k_gemm_acc<<<gsz((long long)N * F2), 256, 0, stream>>>(aggh, W2, hb, h2, N);
    }

    // ---- GAT layer 2 (heads=1, 128 ch) + fused pool ----
    k_coef<<<nb, 256, 0, stream>>>(h2, a2s, a2d, es, ed, N, F2);
    k_gat_node<F2, true><<<gsz((long long)N) * 64, 256, 0, stream>>>(
        rp, csrc, es, ed, h2, b2, nullptr, batch, gb, N);

    // ---- head ----
    k_head_g<<<B, 128, 0, stream>>>(gb, Wg, bg, xc);
    k_head_xt<<<B, 128, 0, stream>>>(te, Wxt, bxt, gamma, beta, rmean, rvar, xc);
    k_head_f1<<<B, 256, 0, stream>>>(xc, Wf1, bf1, f1o);
    k_head_f2<<<B, 256, 0, stream>>>(f1o, Wf2, bf2, f2o);
    k_head_out<<<B, 64, 0, stream>>>(f2o, Wo, bo, (float*)d_out);
}

// Round 4
// 1468.798 us; speedup vs baseline: 3.2304x; 2.1924x over previous
//
#include <hip/hip_runtime.h>
#include <math.h>

static constexpr int F_IN = 78, C1 = 780, F2 = 128, EMB = 320;

__device__ __forceinline__ void esd(const int* src, const int* dst, int E, int e, int& s, int& d) {
    if (e < E) { s = src[e]; d = dst[e]; }
    else       { s = e - E; d = s; }
}

// ---------------- CSR build ----------------
__global__ void k_count(const int* __restrict__ src, const int* __restrict__ dst, int E, int Etot,
                        int* __restrict__ cnt) {
    int e = blockIdx.x * 256 + threadIdx.x;
    if (e >= Etot) return;
    int s, d;
    esd(src, dst, E, e, s, d);
    atomicAdd(&cnt[d], 1);
}

__global__ void k_scan1(const int* __restrict__ in, int* __restrict__ out, int* __restrict__ bsum,
                        int n) {
    __shared__ int tmp[256];
    int t = threadIdx.x;
    int gid = blockIdx.x * 256 + t;
    int v = gid < n ? in[gid] : 0;
    tmp[t] = v;
    __syncthreads();
    for (int off = 1; off < 256; off <<= 1) {
        int u = (t >= off) ? tmp[t - off] : 0;
        __syncthreads();
        tmp[t] += u;
        __syncthreads();
    }
    if (gid < n) out[gid] = tmp[t] - v;
    if (t == 255) bsum[blockIdx.x] = tmp[255];
}

__global__ void k_scan2(int* __restrict__ bsum, int nb) {
    if (threadIdx.x == 0) {
        int run = 0;
        for (int i = 0; i < nb; i++) { int v = bsum[i]; bsum[i] = run; run += v; }
    }
}

__global__ void k_scan3(int* __restrict__ out, const int* __restrict__ bsum, int n, int Etot,
                        int* __restrict__ rp_last) {
    int gid = blockIdx.x * 256 + threadIdx.x;
    if (gid < n) out[gid] += bsum[blockIdx.x];
    if (gid == 0) rp_last[0] = Etot;
}

__global__ void k_scatter(const int* __restrict__ src, const int* __restrict__ dst, int E, int Etot,
                          int* __restrict__ cur, int* __restrict__ csrc) {
    int e = blockIdx.x * 256 + threadIdx.x;
    if (e >= Etot) return;
    int s, d;
    esd(src, dst, E, e, s, d);
    int pos = atomicAdd(&cur[d], 1);
    csrc[pos] = s;
}

// ---------------- tiled GEMM: P[n, 0..390) = x @ W1[:, colbase..colbase+390) ----------------
__global__ void k_gemm_w1(const float* __restrict__ x, const float* __restrict__ W1,
                          int colbase, int ncols, float* __restrict__ out, int ldo, int N) {
    __shared__ __align__(16) float xs[64][80];
    int n0 = blockIdx.x * 64;
    for (int i = threadIdx.x; i < 64 * 80; i += 256) {
        int r = i / 80, k = i - r * 80;
        int n = n0 + r;
        xs[r][k] = (k < F_IN && n < N) ? x[(size_t)n * F_IN + k] : 0.f;
    }
    __syncthreads();
    int ci = threadIdx.x & 127;        // col-pair index in tile
    int rh = (threadIdx.x >> 7) * 32;  // row-half base
    int cp = blockIdx.y * 128 + ci;    // global col-pair in group
    if (2 * cp >= ncols) return;
    const float* w0p = W1 + colbase + 2 * cp;
    for (int nc = rh; nc < rh + 32; nc += 8) {
        float a0[8] = {}, a1[8] = {};
        for (int k = 0; k < 76; k += 4) {
            float2 wa = *(const float2*)&w0p[(k + 0) * C1];
            float2 wb = *(const float2*)&w0p[(k + 1) * C1];
            float2 wc = *(const float2*)&w0p[(k + 2) * C1];
            float2 wd = *(const float2*)&w0p[(k + 3) * C1];
#pragma unroll
            for (int r = 0; r < 8; r++) {
                float4 xv = *(const float4*)&xs[nc + r][k];
                a0[r] = fmaf(xv.x, wa.x, a0[r]); a1[r] = fmaf(xv.x, wa.y, a1[r]);
                a0[r] = fmaf(xv.y, wb.x, a0[r]); a1[r] = fmaf(xv.y, wb.y, a1[r]);
                a0[r] = fmaf(xv.z, wc.x, a0[r]); a1[r] = fmaf(xv.z, wc.y, a1[r]);
                a0[r] = fmaf(xv.w, wd.x, a0[r]); a1[r] = fmaf(xv.w, wd.y, a1[r]);
            }
        }
        {  // k = 76,77 tail (xs 78,79 are zero-padded)
            float2 wa = *(const float2*)&w0p[76 * C1];
            float2 wb = *(const float2*)&w0p[77 * C1];
#pragma unroll
            for (int r = 0; r < 8; r++) {
                float4 xv = *(const float4*)&xs[nc + r][76];
                a0[r] = fmaf(xv.x, wa.x, a0[r]); a1[r] = fmaf(xv.x, wa.y, a1[r]);
                a0[r] = fmaf(xv.y, wb.x, a0[r]); a1[r] = fmaf(xv.y, wb.y, a1[r]);
            }
        }
#pragma unroll
        for (int r = 0; r < 8; r++) {
            int n = n0 + nc + r;
            if (n < N) {
                float2 v = {a0[r], a1[r]};
                *(float2*)&out[(size_t)n * ldo + 2 * cp] = v;
            }
        }
    }
}

// es/ed for 5 heads from P (row stride 390)
__global__ void k_coef5(const float* __restrict__ h, const float* __restrict__ a1s,
                        const float* __restrict__ a1d, int hbase, float* __restrict__ esT,
                        float* __restrict__ edT, int N) {
    int idx = blockIdx.x * 256 + threadIdx.x;
    if (idx >= N * 5) return;
    int hl = idx % 5, n = idx / 5;
    const float* hp = h + (size_t)n * 390 + hl * 78;
    const float* asp = a1s + (size_t)(hbase + hl) * 78;
    const float* adp = a1d + (size_t)(hbase + hl) * 78;
    float s = 0.f, d = 0.f;
    for (int f = 0; f < 78; f++) {
        float v = hp[f];
        s = fmaf(v, asp[f], s);
        d = fmaf(v, adp[f], d);
    }
    esT[(size_t)hl * N + n] = s;
    edT[(size_t)hl * N + n] = d;
}

__global__ void k_coef1(const float* __restrict__ h, const float* __restrict__ as2,
                        const float* __restrict__ ad2, float* __restrict__ es,
                        float* __restrict__ ed, int N) {
    int n = blockIdx.x * 256 + threadIdx.x;
    if (n >= N) return;
    const float* hp = h + (size_t)n * F2;
    float s = 0.f, d = 0.f;
    for (int f = 0; f < F2; f++) {
        float v = hp[f];
        s = fmaf(v, as2[f], s);
        d = fmaf(v, ad2[f], d);
    }
    es[n] = s;
    ed[n] = d;
}

// ---------------- fused per-node GAT: online softmax + aggregate + epilogue ----------------
template <int F, bool POOL>
__global__ void k_gat(const int* __restrict__ rp, const int* __restrict__ csrc,
                      const float* __restrict__ es, const float* __restrict__ ed,
                      const float* __restrict__ h, int ldh, const float* __restrict__ bias,
                      float* __restrict__ out, int ldo, const int* __restrict__ batch,
                      unsigned* __restrict__ gb, int N) {
    int node = blockIdx.x * 4 + (threadIdx.x >> 6);
    if (node >= N) return;
    int lane = threadIdx.x & 63;
    int beg = rp[node], end = rp[node + 1];
    float edn = ed[node];

    // pass AB: online max + sum (edge-parallel across lanes)
    float m = -3.0e38f, ssum = 0.f;
    for (int e = beg + lane; e < end; e += 64) {
        int s = csrc[e];
        float v = es[s] + edn;
        v = v >= 0.f ? v : 0.2f * v;
        if (v > m) { ssum = ssum * __expf(m - v) + 1.f; m = v; }
        else ssum += __expf(v - m);
    }
    for (int off = 32; off; off >>= 1) {
        float om = __shfl_xor(m, off), os = __shfl_xor(ssum, off);
        float nm = fmaxf(m, om);
        ssum = ssum * __expf(m - nm) + os * __expf(om - nm);
        m = nm;
    }
    float inv = 1.f / ssum;

    // pass C: aggregate (sequential over edges, channel-parallel)
    float acc0 = 0.f, acc1 = 0.f;
    for (int e = beg; e < end; e++) {
        int s = csrc[e];
        float v = es[s] + edn;
        v = v >= 0.f ? v : 0.2f * v;
        float a = __expf(v - m) * inv;
        const float* hp = h + (size_t)s * ldh;
        acc0 = fmaf(a, hp[lane], acc0);
        if (F > 64) {
            if (F >= 128 || lane < F - 64) acc1 = fmaf(a, hp[64 + lane], acc1);
        }
    }

    if (!POOL) {
        float v0 = acc0 + bias[lane];
        out[(size_t)node * ldo + lane] = v0 > 0.f ? v0 : expm1f(v0);
        if (F > 64 && lane < F - 64) {
            float v1 = acc1 + bias[64 + lane];
            out[(size_t)node * ldo + 64 + lane] = v1 > 0.f ? v1 : expm1f(v1);
        }
    } else {
        unsigned* gp = gb + (size_t)batch[node] * F;
        float v0 = fmaxf(acc0 + bias[lane], 0.f);
        atomicMax(&gp[lane], __float_as_uint(v0));
        float v1 = fmaxf(acc1 + bias[64 + lane], 0.f);
        atomicMax(&gp[64 + lane], __float_as_uint(v1));
    }
}

// ---------------- h2 += agg(5 heads) @ W2-slice, accumulators in registers ----------------
__global__ void k_gemm_acc5(const float* __restrict__ agg, const float* __restrict__ W2,
                            int kbase, float* __restrict__ h2, int N) {
    __shared__ __align__(16) float as_[64][80];
    int n0 = blockIdx.x * 64;
    int ci = threadIdx.x & 63;         // col pair -> cols 2ci, 2ci+1
    int r0 = (threadIdx.x >> 6) * 16;  // 4 row quarters
    float a0[16] = {}, a1[16] = {};
    for (int hl = 0; hl < 5; hl++) {
        __syncthreads();
        for (int i = threadIdx.x; i < 64 * 80; i += 256) {
            int r = i / 80, k = i - r * 80;
            int n = n0 + r;
            as_[r][k] = (k < 78 && n < N) ? agg[(size_t)n * 390 + hl * 78 + k] : 0.f;
        }
        __syncthreads();
        const float* wp = W2 + (size_t)(kbase + hl * 78) * F2 + 2 * ci;
        for (int k = 0; k < 76; k += 4) {
            float2 wa = *(const float2*)&wp[(k + 0) * F2];
            float2 wb = *(const float2*)&wp[(k + 1) * F2];
            float2 wc = *(const float2*)&wp[(k + 2) * F2];
            float2 wd = *(const float2*)&wp[(k + 3) * F2];
#pragma unroll
            for (int r = 0; r < 16; r++) {
                float4 xv = *(const float4*)&as_[r0 + r][k];
                a0[r] = fmaf(xv.x, wa.x, a0[r]); a1[r] = fmaf(xv.x, wa.y, a1[r]);
                a0[r] = fmaf(xv.y, wb.x, a0[r]); a1[r] = fmaf(xv.y, wb.y, a1[r]);
                a0[r] = fmaf(xv.z, wc.x, a0[r]); a1[r] = fmaf(xv.z, wc.y, a1[r]);
                a0[r] = fmaf(xv.w, wd.x, a0[r]); a1[r] = fmaf(xv.w, wd.y, a1[r]);
            }
        }
        {
            float2 wa = *(const float2*)&wp[76 * F2];
            float2 wb = *(const float2*)&wp[77 * F2];
#pragma unroll
            for (int r = 0; r < 16; r++) {
                float4 xv = *(const float4*)&as_[r0 + r][76];
                a0[r] = fmaf(xv.x, wa.x, a0[r]); a1[r] = fmaf(xv.x, wa.y, a1[r]);
                a0[r] = fmaf(xv.y, wb.x, a0[r]); a1[r] = fmaf(xv.y, wb.y, a1[r]);
            }
        }
    }
#pragma unroll
    for (int r = 0; r < 16; r++) {
        int n = n0 + r0 + r;
        if (n < N) {
            float2* h2p = (float2*)&h2[(size_t)n * F2 + 2 * ci];
            float2 cur = *h2p;
            cur.x += a0[r];
            cur.y += a1[r];
            *h2p = cur;
        }
    }
}

// ---------------- head ----------------
__global__ void k_head_g(const unsigned* __restrict__ gbits, const float* __restrict__ Wg,
                         const float* __restrict__ bg, float* __restrict__ xc) {
    int b = blockIdx.x, c = threadIdx.x;
    __shared__ float srow[F2];
    srow[c] = __uint_as_float(gbits[(size_t)b * F2 + c]);
    __syncthreads();
    float acc = bg[c];
    for (int k = 0; k < F2; k++) acc = fmaf(srow[k], Wg[k * F2 + c], acc);
    xc[(size_t)b * 256 + c] = fmaxf(acc, 0.f);
}

__global__ void k_head_xt(const float* __restrict__ te, const float* __restrict__ Wxt,
                          const float* __restrict__ bxt, const float* __restrict__ gamma,
                          const float* __restrict__ beta, const float* __restrict__ rmean,
                          const float* __restrict__ rvar, float* __restrict__ xc) {
    int b = blockIdx.x, c = threadIdx.x;
    __shared__ float srow[EMB];
    for (int k = c; k < EMB; k += 128) srow[k] = te[(size_t)b * EMB + k];
    __syncthreads();
    float acc = bxt[c];
    for (int k = 0; k < EMB; k++) acc = fmaf(srow[k], Wxt[k * F2 + c], acc);
    acc = (acc - rmean[c]) * rsqrtf(rvar[c] + 1e-5f) * gamma[c] + beta[c];
    xc[(size_t)b * 256 + 128 + c] = fmaxf(acc, 0.f);
}

__global__ void k_head_f1(const float* __restrict__ xc, const float* __restrict__ W,
                          const float* __restrict__ bias, float* __restrict__ o) {
    int b = blockIdx.x;
    __shared__ float srow[256];
    srow[threadIdx.x] = xc[(size_t)b * 256 + threadIdx.x];
    __syncthreads();
    for (int col = threadIdx.x; col < 1024; col += 256) {
        float acc = bias[col];
        for (int k = 0; k < 256; k++) acc = fmaf(srow[k], W[k * 1024 + col], acc);
        o[(size_t)b * 1024 + col] = fmaxf(acc, 0.f);
    }
}

__global__ void k_head_f2(const float* __restrict__ in, const float* __restrict__ W,
                          const float* __restrict__ bias, float* __restrict__ o) {
    int b = blockIdx.x;
    int col = threadIdx.x;
    __shared__ float srow[1024];
    for (int k = col; k < 1024; k += 256) srow[k] = in[(size_t)b * 1024 + k];
    __syncthreads();
    float acc = bias[col];
    for (int k = 0; k < 1024; k++) acc = fmaf(srow[k], W[k * 256 + col], acc);
    o[(size_t)b * 256 + col] = fmaxf(acc, 0.f);
}

__global__ void k_head_out(const float* __restrict__ in, const float* __restrict__ Wo,
                           const float* __restrict__ bo, float* __restrict__ out) {
    int b = blockIdx.x;
    float acc = 0.f;
    for (int k = threadIdx.x; k < 256; k += 64) acc = fmaf(in[(size_t)b * 256 + k], Wo[k], acc);
    for (int off = 32; off; off >>= 1) acc += __shfl_down(acc, off);
    if (threadIdx.x == 0) out[b] = acc + bo[0];
}

extern "C" void kernel_launch(void* const* d_in, const int* in_sizes, int n_in,
                              void* d_out, int out_size, void* d_ws, size_t ws_size,
                              hipStream_t stream) {
    const float* x     = (const float*)d_in[0];
    const int*   ei    = (const int*)d_in[1];
    const int*   batch = (const int*)d_in[2];
    const float* te    = (const float*)d_in[3];
    const float* W1    = (const float*)d_in[4];
    const float* a1s   = (const float*)d_in[5];
    const float* a1d   = (const float*)d_in[6];
    const float* b1    = (const float*)d_in[7];
    const float* W2    = (const float*)d_in[8];
    const float* a2s   = (const float*)d_in[9];
    const float* a2d   = (const float*)d_in[10];
    const float* b2    = (const float*)d_in[11];
    const float* Wg    = (const float*)d_in[12];
    const float* bg    = (const float*)d_in[13];
    const float* Wxt   = (const float*)d_in[14];
    const float* bxt   = (const float*)d_in[15];
    const float* gamma = (const float*)d_in[16];
    const float* beta  = (const float*)d_in[17];
    const float* rmean = (const float*)d_in[18];
    const float* rvar  = (const float*)d_in[19];
    const float* Wf1   = (const float*)d_in[20];
    const float* bf1   = (const float*)d_in[21];
    const float* Wf2   = (const float*)d_in[22];
    const float* bf2   = (const float*)d_in[23];
    const float* Wo    = (const float*)d_in[24];
    const float* bo    = (const float*)d_in[25];

    const int N = in_sizes[0] / F_IN;
    const int E = in_sizes[1] / 2;
    const int B = in_sizes[3] / EMB;
    const int Etot = E + N;
    const int* src = ei;
    const int* dst = ei + E;

    char* p = (char*)d_ws;
    auto alloc = [&](size_t bytes) -> void* {
        void* r = p;
        p += (bytes + 255) & ~(size_t)255;
        return r;
    };
    float*    P    = (float*)alloc((size_t)N * 390 * 4);  // h1 for 5 heads (78 MB)
    float*    Q    = (float*)alloc((size_t)N * 390 * 4);  // elu'd agg for 5 heads (78 MB)
    float*    h2   = (float*)alloc((size_t)N * F2 * 4);   // 25.6 MB
    float*    esT  = (float*)alloc((size_t)N * 5 * 4);
    float*    edT  = (float*)alloc((size_t)N * 5 * 4);
    int*      cnt  = (int*)alloc((size_t)N * 4);
    int*      rp   = (int*)alloc((size_t)(N + 1) * 4);
    int*      cur  = (int*)alloc((size_t)N * 4);
    int*      csrc = (int*)alloc((size_t)Etot * 4);
    int*      bsum = (int*)alloc((size_t)1024 * 4);
    unsigned* gb   = (unsigned*)alloc((size_t)B * F2 * 4);
    float*    xc   = (float*)alloc((size_t)B * 256 * 4);
    float*    f1o  = (float*)alloc((size_t)B * 1024 * 4);
    float*    f2o  = (float*)alloc((size_t)B * 256 * 4);

    auto gsz = [](long long t) { return (int)((t + 255) / 256); };
    const int nb = gsz(N);
    const int nwave = (N + 3) / 4;  // k_gat blocks (4 nodes/block)

    // ---- CSR build ----
    hipMemsetAsync(cnt, 0, (size_t)N * 4, stream);
    k_count<<<gsz(Etot), 256, 0, stream>>>(src, dst, E, Etot, cnt);
    k_scan1<<<nb, 256, 0, stream>>>(cnt, rp, bsum, N);
    k_scan2<<<1, 64, 0, stream>>>(bsum, nb);
    k_scan3<<<nb, 256, 0, stream>>>(rp, bsum, N, Etot, rp + N);
    hipMemcpyAsync(cur, rp, (size_t)N * 4, hipMemcpyDeviceToDevice, stream);
    k_scatter<<<gsz(Etot), 256, 0, stream>>>(src, dst, E, Etot, cur, csrc);

    hipMemsetAsync(h2, 0, (size_t)N * F2 * 4, stream);
    hipMemsetAsync(gb, 0, (size_t)B * F2 * 4, stream);

    // ---- GAT layer 1: 2 groups of 5 heads ----
    for (int g = 0; g < 2; g++) {
        int hbase = g * 5;
        k_gemm_w1<<<dim3((N + 63) / 64, 2), 256, 0, stream>>>(x, W1, g * 390, 390, P, 390, N);
        k_coef5<<<gsz((long long)N * 5), 256, 0, stream>>>(P, a1s, a1d, hbase, esT, edT, N);
        for (int hl = 0; hl < 5; hl++) {
            k_gat<78, false><<<nwave, 256, 0, stream>>>(
                rp, csrc, esT + (size_t)hl * N, edT + (size_t)hl * N, P + hl * 78, 390,
                b1 + (size_t)(hbase + hl) * 78, Q + hl * 78, 390, nullptr, nullptr, N);
        }
        k_gemm_acc5<<<(N + 63) / 64, 256, 0, stream>>>(Q, W2, g * 390, h2, N);
    }

    // ---- GAT layer 2 (heads=1, 128 ch) + fused pool ----
    k_coef1<<<nb, 256, 0, stream>>>(h2, a2s, a2d, esT, edT, N);
    k_gat<F2, true><<<nwave, 256, 0, stream>>>(rp, csrc, esT, edT, h2, F2, b2, nullptr, 0, batch,
                                               gb, N);

    // ---- head ----
    k_head_g<<<B, 128, 0, stream>>>(gb, Wg, bg, xc);
    k_head_xt<<<B, 128, 0, stream>>>(te, Wxt, bxt, gamma, beta, rmean, rvar, xc);
    k_head_f1<<<B, 256, 0, stream>>>(xc, Wf1, bf1, f1o);
    k_head_f2<<<B, 256, 0, stream>>>(f1o, Wf2, bf2, f2o);
    k_head_out<<<B, 64, 0, stream>>>(f2o, Wo, bo, (float*)d_out);
}

// Round 5
// 880.751 us; speedup vs baseline: 5.3872x; 1.6677x over previous
//
#include <hip/hip_runtime.h>
#include <math.h>

static constexpr int F_IN = 78, C1 = 780, F2 = 128, EMB = 320;

__device__ __forceinline__ void esd(const int* src, const int* dst, int E, int e, int& s, int& d) {
    if (e < E) { s = src[e]; d = dst[e]; }
    else       { s = e - E; d = s; }
}

// ---------------- CSR build ----------------
__global__ void k_count(const int* __restrict__ src, const int* __restrict__ dst, int E, int Etot,
                        int* __restrict__ cnt) {
    int e = blockIdx.x * 256 + threadIdx.x;
    if (e >= Etot) return;
    int s, d;
    esd(src, dst, E, e, s, d);
    atomicAdd(&cnt[d], 1);
}

__global__ void k_scan1(const int* __restrict__ in, int* __restrict__ out, int* __restrict__ bsum,
                        int n) {
    __shared__ int tmp[256];
    int t = threadIdx.x;
    int gid = blockIdx.x * 256 + t;
    int v = gid < n ? in[gid] : 0;
    tmp[t] = v;
    __syncthreads();
    for (int off = 1; off < 256; off <<= 1) {
        int u = (t >= off) ? tmp[t - off] : 0;
        __syncthreads();
        tmp[t] += u;
        __syncthreads();
    }
    if (gid < n) out[gid] = tmp[t] - v;
    if (t == 255) bsum[blockIdx.x] = tmp[255];
}

__global__ void k_scan2(int* __restrict__ bsum, int nb) {
    if (threadIdx.x == 0) {
        int run = 0;
        for (int i = 0; i < nb; i++) { int v = bsum[i]; bsum[i] = run; run += v; }
    }
}

__global__ void k_scan3(int* __restrict__ out, const int* __restrict__ bsum, int n, int Etot,
                        int* __restrict__ rp_last) {
    int gid = blockIdx.x * 256 + threadIdx.x;
    if (gid < n) out[gid] += bsum[blockIdx.x];
    if (gid == 0) rp_last[0] = Etot;
}

__global__ void k_scatter(const int* __restrict__ src, const int* __restrict__ dst, int E, int Etot,
                          int* __restrict__ cur, int* __restrict__ csrc) {
    int e = blockIdx.x * 256 + threadIdx.x;
    if (e >= Etot) return;
    int s, d;
    esd(src, dst, E, e, s, d);
    int pos = atomicAdd(&cur[d], 1);
    csrc[pos] = s;
}

// ---------------- tiled GEMM: P[n, 0..390) = x @ W1[:, colbase+0..390) ----------------
__global__ void k_gemm_w1(const float* __restrict__ x, const float* __restrict__ W1,
                          int colbase, float* __restrict__ out, int N) {
    __shared__ __align__(16) float xs[32][80];
    int n0 = blockIdx.x * 32;
    for (int i = threadIdx.x; i < 32 * 80; i += 256) {
        int r = i / 80, k = i - r * 80;
        int n = n0 + r;
        xs[r][k] = (k < F_IN && n < N) ? x[(size_t)n * F_IN + k] : 0.f;
    }
    __syncthreads();
    int ci = threadIdx.x & 127;
    int rh = (threadIdx.x >> 7) * 16;
    int cp = blockIdx.y * 128 + ci;
    if (2 * cp >= 390) return;
    const float* w0p = W1 + colbase + 2 * cp;
    for (int nc = rh; nc < rh + 16; nc += 8) {
        float a0[8] = {}, a1[8] = {};
        for (int k = 0; k < 76; k += 4) {
            float2 wa = *(const float2*)&w0p[(k + 0) * C1];
            float2 wb = *(const float2*)&w0p[(k + 1) * C1];
            float2 wc = *(const float2*)&w0p[(k + 2) * C1];
            float2 wd = *(const float2*)&w0p[(k + 3) * C1];
#pragma unroll
            for (int r = 0; r < 8; r++) {
                float4 xv = *(const float4*)&xs[nc + r][k];
                a0[r] = fmaf(xv.x, wa.x, a0[r]); a1[r] = fmaf(xv.x, wa.y, a1[r]);
                a0[r] = fmaf(xv.y, wb.x, a0[r]); a1[r] = fmaf(xv.y, wb.y, a1[r]);
                a0[r] = fmaf(xv.z, wc.x, a0[r]); a1[r] = fmaf(xv.z, wc.y, a1[r]);
                a0[r] = fmaf(xv.w, wd.x, a0[r]); a1[r] = fmaf(xv.w, wd.y, a1[r]);
            }
        }
        {
            float2 wa = *(const float2*)&w0p[76 * C1];
            float2 wb = *(const float2*)&w0p[77 * C1];
#pragma unroll
            for (int r = 0; r < 8; r++) {
                float4 xv = *(const float4*)&xs[nc + r][76];
                a0[r] = fmaf(xv.x, wa.x, a0[r]); a1[r] = fmaf(xv.x, wa.y, a1[r]);
                a0[r] = fmaf(xv.y, wb.x, a0[r]); a1[r] = fmaf(xv.y, wb.y, a1[r]);
            }
        }
#pragma unroll
        for (int r = 0; r < 8; r++) {
            int n = n0 + nc + r;
            if (n < N) {
                float2 v = {a0[r], a1[r]};
                *(float2*)&out[(size_t)n * 390 + 2 * cp] = v;
            }
        }
    }
}

// es/ed for 5 heads, padded layout [n*8 + hl]
__global__ void k_coef5(const float* __restrict__ h, const float* __restrict__ a1s,
                        const float* __restrict__ a1d, int hbase, float* __restrict__ es5,
                        float* __restrict__ ed5, int N) {
    int idx = blockIdx.x * 256 + threadIdx.x;
    if (idx >= N * 5) return;
    int hl = idx % 5, n = idx / 5;
    const float* hp = h + (size_t)n * 390 + hl * 78;
    const float* asp = a1s + (size_t)(hbase + hl) * 78;
    const float* adp = a1d + (size_t)(hbase + hl) * 78;
    float s = 0.f, d = 0.f;
    for (int f = 0; f < 78; f++) {
        float v = hp[f];
        s = fmaf(v, asp[f], s);
        d = fmaf(v, adp[f], d);
    }
    es5[(size_t)n * 8 + hl] = s;
    ed5[(size_t)n * 8 + hl] = d;
}

__global__ void k_coef1(const float* __restrict__ h, const float* __restrict__ as2,
                        const float* __restrict__ ad2, float* __restrict__ es,
                        float* __restrict__ ed, int N) {
    int n = blockIdx.x * 256 + threadIdx.x;
    if (n >= N) return;
    const float* hp = h + (size_t)n * F2;
    float s = 0.f, d = 0.f;
    for (int f = 0; f < F2; f++) {
        float v = hp[f];
        s = fmaf(v, as2[f], s);
        d = fmaf(v, ad2[f], d);
    }
    es[n] = s;
    ed[n] = d;
}

// ---------------- fused 5-head GAT: softmax + aggregate + elu, one wave per node ----------------
__global__ void k_gat5(const int* __restrict__ rp, const int* __restrict__ csrc,
                       const float* __restrict__ es5, const float* __restrict__ ed5,
                       const float* __restrict__ h, const float* __restrict__ bias,
                       float* __restrict__ out, int N) {
    int node = blockIdx.x * 4 + (threadIdx.x >> 6);
    if (node >= N) return;
    int lane = threadIdx.x & 63;
    int beg = rp[node], end = rp[node + 1];

    float edn[5];
    {
        float4 e4 = *(const float4*)&ed5[(size_t)node * 8];
        edn[0] = e4.x; edn[1] = e4.y; edn[2] = e4.z; edn[3] = e4.w;
        edn[4] = ed5[(size_t)node * 8 + 4];
    }

    float m[5], ss[5], v0[5];
    int s0 = 0;
#pragma unroll
    for (int hl = 0; hl < 5; hl++) { m[hl] = -3.0e38f; ss[hl] = 0.f; v0[hl] = -3.0e38f; }

    // pass AB: online max+sum, lane-parallel over edges
    for (int cb = beg; cb < end; cb += 64) {
        int e = cb + lane;
        bool act = e < end;
        int s = act ? csrc[e] : 0;
        float v[5];
        if (act) {
            float4 q4 = *(const float4*)&es5[(size_t)s * 8];
            float q4b = es5[(size_t)s * 8 + 4];
            v[0] = q4.x + edn[0]; v[1] = q4.y + edn[1]; v[2] = q4.z + edn[2];
            v[3] = q4.w + edn[3]; v[4] = q4b + edn[4];
#pragma unroll
            for (int hl = 0; hl < 5; hl++) v[hl] = v[hl] >= 0.f ? v[hl] : 0.2f * v[hl];
        } else {
#pragma unroll
            for (int hl = 0; hl < 5; hl++) v[hl] = -3.0e38f;
        }
        if (cb == beg) {
            s0 = s;
#pragma unroll
            for (int hl = 0; hl < 5; hl++) v0[hl] = v[hl];
        }
#pragma unroll
        for (int hl = 0; hl < 5; hl++) {
            float vv = v[hl];
            if (vv > m[hl]) { ss[hl] = ss[hl] * __expf(m[hl] - vv) + 1.f; m[hl] = vv; }
            else ss[hl] += __expf(vv - m[hl]);
        }
    }
#pragma unroll
    for (int off = 32; off; off >>= 1) {
#pragma unroll
        for (int hl = 0; hl < 5; hl++) {
            float om = __shfl_xor(m[hl], off), os = __shfl_xor(ss[hl], off);
            float nm = fmaxf(m[hl], om);
            ss[hl] = ss[hl] * __expf(m[hl] - nm) + os * __expf(om - nm);
            m[hl] = nm;
        }
    }
    float inv[5];
#pragma unroll
    for (int hl = 0; hl < 5; hl++) inv[hl] = 1.f / ss[hl];

    // pass C: per-lane alpha, broadcast via shfl; channel-parallel aggregate
    float acc[7] = {0.f, 0.f, 0.f, 0.f, 0.f, 0.f, 0.f};
    for (int cb = beg; cb < end; cb += 64) {
        int cnt = min(64, end - cb);
        int s;
        float p[5];
        if (cb == beg) {
            s = s0;
#pragma unroll
            for (int hl = 0; hl < 5; hl++) p[hl] = __expf(v0[hl] - m[hl]) * inv[hl];
        } else {
            int e = cb + lane;
            bool act = e < end;
            s = act ? csrc[e] : 0;
            if (act) {
                float4 q4 = *(const float4*)&es5[(size_t)s * 8];
                float q4b = es5[(size_t)s * 8 + 4];
                float v[5];
                v[0] = q4.x + edn[0]; v[1] = q4.y + edn[1]; v[2] = q4.z + edn[2];
                v[3] = q4.w + edn[3]; v[4] = q4b + edn[4];
#pragma unroll
                for (int hl = 0; hl < 5; hl++) {
                    float vv = v[hl] >= 0.f ? v[hl] : 0.2f * v[hl];
                    p[hl] = __expf(vv - m[hl]) * inv[hl];
                }
            } else {
#pragma unroll
                for (int hl = 0; hl < 5; hl++) p[hl] = 0.f;
            }
        }
        for (int i = 0; i < cnt; i++) {
            int sb = __shfl(s, i);
            float a0 = __shfl(p[0], i), a1 = __shfl(p[1], i), a2 = __shfl(p[2], i),
                  a3 = __shfl(p[3], i), a4 = __shfl(p[4], i);
            const float* hp = h + (size_t)sb * 390;
            acc[0] = fmaf(a0, hp[lane], acc[0]);
            { float a = (64 + lane < 78) ? a0 : a1;   acc[1] = fmaf(a, hp[64 + lane], acc[1]); }
            { float a = (128 + lane < 156) ? a1 : a2; acc[2] = fmaf(a, hp[128 + lane], acc[2]); }
            { float a = (192 + lane < 234) ? a2 : a3; acc[3] = fmaf(a, hp[192 + lane], acc[3]); }
            { float a = (256 + lane < 312) ? a3 : a4; acc[4] = fmaf(a, hp[256 + lane], acc[4]); }
            acc[5] = fmaf(a4, hp[320 + lane], acc[5]);
            if (lane < 6) acc[6] = fmaf(a4, hp[384 + lane], acc[6]);
        }
    }

    float* op = out + (size_t)node * 390;
#pragma unroll
    for (int j = 0; j < 6; j++) {
        int c = j * 64 + lane;
        float t = acc[j] + bias[c];
        op[c] = t > 0.f ? t : expm1f(t);
    }
    if (lane < 6) {
        int c = 384 + lane;
        float t = acc[6] + bias[c];
        op[c] = t > 0.f ? t : expm1f(t);
    }
}

// ---------------- layer-2 GAT (1 head, 128 ch) + fused relu/max-pool ----------------
__global__ void k_gatP(const int* __restrict__ rp, const int* __restrict__ csrc,
                       const float* __restrict__ es, const float* __restrict__ ed,
                       const float* __restrict__ h, const float* __restrict__ b2,
                       const int* __restrict__ batch, unsigned* __restrict__ gb, int N) {
    int node = blockIdx.x * 4 + (threadIdx.x >> 6);
    if (node >= N) return;
    int lane = threadIdx.x & 63;
    int beg = rp[node], end = rp[node + 1];
    float edn = ed[node];

    float m = -3.0e38f, ss = 0.f, v0 = -3.0e38f;
    int s0 = 0;
    for (int cb = beg; cb < end; cb += 64) {
        int e = cb + lane;
        bool act = e < end;
        int s = act ? csrc[e] : 0;
        float v = -3.0e38f;
        if (act) {
            v = es[s] + edn;
            v = v >= 0.f ? v : 0.2f * v;
        }
        if (cb == beg) { s0 = s; v0 = v; }
        if (v > m) { ss = ss * __expf(m - v) + 1.f; m = v; }
        else ss += __expf(v - m);
    }
#pragma unroll
    for (int off = 32; off; off >>= 1) {
        float om = __shfl_xor(m, off), os = __shfl_xor(ss, off);
        float nm = fmaxf(m, om);
        ss = ss * __expf(m - nm) + os * __expf(om - nm);
        m = nm;
    }
    float inv = 1.f / ss;

    float acc0 = 0.f, acc1 = 0.f;
    for (int cb = beg; cb < end; cb += 64) {
        int cnt = min(64, end - cb);
        int s;
        float p;
        if (cb == beg) {
            s = s0;
            p = __expf(v0 - m) * inv;
        } else {
            int e = cb + lane;
            bool act = e < end;
            s = act ? csrc[e] : 0;
            p = 0.f;
            if (act) {
                float v = es[s] + edn;
                v = v >= 0.f ? v : 0.2f * v;
                p = __expf(v - m) * inv;
            }
        }
        for (int i = 0; i < cnt; i++) {
            int sb = __shfl(s, i);
            float a = __shfl(p, i);
            const float* hp = h + (size_t)sb * F2;
            acc0 = fmaf(a, hp[lane], acc0);
            acc1 = fmaf(a, hp[64 + lane], acc1);
        }
    }

    unsigned* gp = gb + (size_t)batch[node] * F2;
    float t0 = fmaxf(acc0 + b2[lane], 0.f);
    atomicMax(&gp[lane], __float_as_uint(t0));
    float t1 = fmaxf(acc1 + b2[64 + lane], 0.f);
    atomicMax(&gp[64 + lane], __float_as_uint(t1));
}

// ---------------- h2 += agg(5 heads) @ W2-slice ----------------
__global__ void k_gemm_acc5(const float* __restrict__ agg, const float* __restrict__ W2,
                            int kbase, float* __restrict__ h2, int N) {
    __shared__ __align__(16) float as_[32][80];
    int n0 = blockIdx.x * 32;
    int ci = threadIdx.x & 63;
    int r0 = (threadIdx.x >> 6) * 8;
    float a0[8] = {}, a1[8] = {};
    for (int hl = 0; hl < 5; hl++) {
        __syncthreads();
        for (int i = threadIdx.x; i < 32 * 80; i += 256) {
            int r = i / 80, k = i - r * 80;
            int n = n0 + r;
            as_[r][k] = (k < 78 && n < N) ? agg[(size_t)n * 390 + hl * 78 + k] : 0.f;
        }
        __syncthreads();
        const float* wp = W2 + (size_t)(kbase + hl * 78) * F2 + 2 * ci;
        for (int k = 0; k < 76; k += 4) {
            float2 wa = *(const float2*)&wp[(k + 0) * F2];
            float2 wb = *(const float2*)&wp[(k + 1) * F2];
            float2 wc = *(const float2*)&wp[(k + 2) * F2];
            float2 wd = *(const float2*)&wp[(k + 3) * F2];
#pragma unroll
            for (int r = 0; r < 8; r++) {
                float4 xv = *(const float4*)&as_[r0 + r][k];
                a0[r] = fmaf(xv.x, wa.x, a0[r]); a1[r] = fmaf(xv.x, wa.y, a1[r]);
                a0[r] = fmaf(xv.y, wb.x, a0[r]); a1[r] = fmaf(xv.y, wb.y, a1[r]);
                a0[r] = fmaf(xv.z, wc.x, a0[r]); a1[r] = fmaf(xv.z, wc.y, a1[r]);
                a0[r] = fmaf(xv.w, wd.x, a0[r]); a1[r] = fmaf(xv.w, wd.y, a1[r]);
            }
        }
        {
            float2 wa = *(const float2*)&wp[76 * F2];
            float2 wb = *(const float2*)&wp[77 * F2];
#pragma unroll
            for (int r = 0; r < 8; r++) {
                float4 xv = *(const float4*)&as_[r0 + r][76];
                a0[r] = fmaf(xv.x, wa.x, a0[r]); a1[r] = fmaf(xv.x, wa.y, a1[r]);
                a0[r] = fmaf(xv.y, wb.x, a0[r]); a1[r] = fmaf(xv.y, wb.y, a1[r]);
            }
        }
    }
#pragma unroll
    for (int r = 0; r < 8; r++) {
        int n = n0 + r0 + r;
        if (n < N) {
            float2* h2p = (float2*)&h2[(size_t)n * F2 + 2 * ci];
            float2 cur = *h2p;
            cur.x += a0[r];
            cur.y += a1[r];
            *h2p = cur;
        }
    }
}

// ---------------- head ----------------
__global__ void k_head_g(const unsigned* __restrict__ gbits, const float* __restrict__ Wg,
                         const float* __restrict__ bg, float* __restrict__ xc) {
    int b = blockIdx.x, c = threadIdx.x;
    __shared__ float srow[F2];
    srow[c] = __uint_as_float(gbits[(size_t)b * F2 + c]);
    __syncthreads();
    float acc = bg[c];
    for (int k = 0; k < F2; k++) acc = fmaf(srow[k], Wg[k * F2 + c], acc);
    xc[(size_t)b * 256 + c] = fmaxf(acc, 0.f);
}

__global__ void k_head_xt(const float* __restrict__ te, const float* __restrict__ Wxt,
                          const float* __restrict__ bxt, const float* __restrict__ gamma,
                          const float* __restrict__ beta, const float* __restrict__ rmean,
                          const float* __restrict__ rvar, float* __restrict__ xc) {
    int b = blockIdx.x, c = threadIdx.x;
    __shared__ float srow[EMB];
    for (int k = c; k < EMB; k += 128) srow[k] = te[(size_t)b * EMB + k];
    __syncthreads();
    float acc = bxt[c];
    for (int k = 0; k < EMB; k++) acc = fmaf(srow[k], Wxt[k * F2 + c], acc);
    acc = (acc - rmean[c]) * rsqrtf(rvar[c] + 1e-5f) * gamma[c] + beta[c];
    xc[(size_t)b * 256 + 128 + c] = fmaxf(acc, 0.f);
}

__global__ void k_head_f1(const float* __restrict__ xc, const float* __restrict__ W,
                          const float* __restrict__ bias, float* __restrict__ o) {
    int b = blockIdx.x;
    __shared__ float srow[256];
    srow[threadIdx.x] = xc[(size_t)b * 256 + threadIdx.x];
    __syncthreads();
    for (int col = threadIdx.x; col < 1024; col += 256) {
        float acc = bias[col];
        for (int k = 0; k < 256; k++) acc = fmaf(srow[k], W[k * 1024 + col], acc);
        o[(size_t)b * 1024 + col] = fmaxf(acc, 0.f);
    }
}

__global__ void k_head_f2(const float* __restrict__ in, const float* __restrict__ W,
                          const float* __restrict__ bias, float* __restrict__ o) {
    int b = blockIdx.x;
    int col = threadIdx.x;
    __shared__ float srow[1024];
    for (int k = col; k < 1024; k += 256) srow[k] = in[(size_t)b * 1024 + k];
    __syncthreads();
    float acc = bias[col];
    for (int k = 0; k < 1024; k++) acc = fmaf(srow[k], W[k * 256 + col], acc);
    o[(size_t)b * 256 + col] = fmaxf(acc, 0.f);
}

__global__ void k_head_out(const float* __restrict__ in, const float* __restrict__ Wo,
                           const float* __restrict__ bo, float* __restrict__ out) {
    int b = blockIdx.x;
    float acc = 0.f;
    for (int k = threadIdx.x; k < 256; k += 64) acc = fmaf(in[(size_t)b * 256 + k], Wo[k], acc);
    for (int off = 32; off; off >>= 1) acc += __shfl_down(acc, off);
    if (threadIdx.x == 0) out[b] = acc + bo[0];
}

extern "C" void kernel_launch(void* const* d_in, const int* in_sizes, int n_in,
                              void* d_out, int out_size, void* d_ws, size_t ws_size,
                              hipStream_t stream) {
    const float* x     = (const float*)d_in[0];
    const int*   ei    = (const int*)d_in[1];
    const int*   batch = (const int*)d_in[2];
    const float* te    = (const float*)d_in[3];
    const float* W1    = (const float*)d_in[4];
    const float* a1s   = (const float*)d_in[5];
    const float* a1d   = (const float*)d_in[6];
    const float* b1    = (const float*)d_in[7];
    const float* W2    = (const float*)d_in[8];
    const float* a2s   = (const float*)d_in[9];
    const float* a2d   = (const float*)d_in[10];
    const float* b2    = (const float*)d_in[11];
    const float* Wg    = (const float*)d_in[12];
    const float* bg    = (const float*)d_in[13];
    const float* Wxt   = (const float*)d_in[14];
    const float* bxt   = (const float*)d_in[15];
    const float* gamma = (const float*)d_in[16];
    const float* beta  = (const float*)d_in[17];
    const float* rmean = (const float*)d_in[18];
    const float* rvar  = (const float*)d_in[19];
    const float* Wf1   = (const float*)d_in[20];
    const float* bf1   = (const float*)d_in[21];
    const float* Wf2   = (const float*)d_in[22];
    const float* bf2   = (const float*)d_in[23];
    const float* Wo    = (const float*)d_in[24];
    const float* bo    = (const float*)d_in[25];

    const int N = in_sizes[0] / F_IN;
    const int E = in_sizes[1] / 2;
    const int B = in_sizes[3] / EMB;
    const int Etot = E + N;
    const int* src = ei;
    const int* dst = ei + E;

    char* p = (char*)d_ws;
    auto alloc = [&](size_t bytes) -> void* {
        void* r = p;
        p += (bytes + 255) & ~(size_t)255;
        return r;
    };
    float*    P    = (float*)alloc((size_t)N * 390 * 4);
    float*    Q    = (float*)alloc((size_t)N * 390 * 4);
    float*    h2   = (float*)alloc((size_t)N * F2 * 4);
    float*    es5  = (float*)alloc((size_t)N * 8 * 4);
    float*    ed5  = (float*)alloc((size_t)N * 8 * 4);
    int*      cnt  = (int*)alloc((size_t)N * 4);
    int*      rp   = (int*)alloc((size_t)(N + 1) * 4);
    int*      cur  = (int*)alloc((size_t)N * 4);
    int*      csrc = (int*)alloc((size_t)Etot * 4);
    int*      bsum = (int*)alloc((size_t)1024 * 4);
    unsigned* gb   = (unsigned*)alloc((size_t)B * F2 * 4);
    float*    xc   = (float*)alloc((size_t)B * 256 * 4);
    float*    f1o  = (float*)alloc((size_t)B * 1024 * 4);
    float*    f2o  = (float*)alloc((size_t)B * 256 * 4);

    auto gsz = [](long long t) { return (int)((t + 255) / 256); };
    const int nb = gsz(N);
    const int nwave = (N + 3) / 4;

    // ---- CSR build ----
    hipMemsetAsync(cnt, 0, (size_t)N * 4, stream);
    k_count<<<gsz(Etot), 256, 0, stream>>>(src, dst, E, Etot, cnt);
    k_scan1<<<nb, 256, 0, stream>>>(cnt, rp, bsum, N);
    k_scan2<<<1, 64, 0, stream>>>(bsum, nb);
    k_scan3<<<nb, 256, 0, stream>>>(rp, bsum, N, Etot, rp + N);
    hipMemcpyAsync(cur, rp, (size_t)N * 4, hipMemcpyDeviceToDevice, stream);
    k_scatter<<<gsz(Etot), 256, 0, stream>>>(src, dst, E, Etot, cur, csrc);

    hipMemsetAsync(h2, 0, (size_t)N * F2 * 4, stream);
    hipMemsetAsync(gb, 0, (size_t)B * F2 * 4, stream);

    // ---- GAT layer 1: 2 groups of 5 heads ----
    for (int g = 0; g < 2; g++) {
        k_gemm_w1<<<dim3((N + 31) / 32, 2), 256, 0, stream>>>(x, W1, g * 390, P, N);
        k_coef5<<<gsz((long long)N * 5), 256, 0, stream>>>(P, a1s, a1d, g * 5, es5, ed5, N);
        k_gat5<<<nwave, 256, 0, stream>>>(rp, csrc, es5, ed5, P, b1 + (size_t)g * 390, Q, N);
        k_gemm_acc5<<<(N + 31) / 32, 256, 0, stream>>>(Q, W2, g * 390, h2, N);
    }

    // ---- GAT layer 2 (1 head, 128 ch) + fused pool ----
    k_coef1<<<nb, 256, 0, stream>>>(h2, a2s, a2d, es5, ed5, N);
    k_gatP<<<nwave, 256, 0, stream>>>(rp, csrc, es5, ed5, h2, b2, batch, gb, N);

    // ---- head ----
    k_head_g<<<B, 128, 0, stream>>>(gb, Wg, bg, xc);
    k_head_xt<<<B, 128, 0, stream>>>(te, Wxt, bxt, gamma, beta, rmean, rvar, xc);
    k_head_f1<<<B, 256, 0, stream>>>(xc, Wf1, bf1, f1o);
    k_head_f2<<<B, 256, 0, stream>>>(f1o, Wf2, bf2, f2o);
    k_head_out<<<B, 64, 0, stream>>>(f2o, Wo, bo, (float*)d_out);
}

// Round 6
// 809.493 us; speedup vs baseline: 5.8615x; 1.0880x over previous
//
#include <hip/hip_runtime.h>
#include <hip/hip_fp16.h>
#include <math.h>

static constexpr int F_IN = 78, C1 = 780, F2 = 128, EMB = 320;

__device__ __forceinline__ void esd(const int* src, const int* dst, int E, int e, int& s, int& d) {
    if (e < E) { s = src[e]; d = dst[e]; }
    else       { s = e - E; d = s; }
}

// ---------------- CSR build ----------------
__global__ void k_count(const int* __restrict__ src, const int* __restrict__ dst, int E, int Etot,
                        int* __restrict__ cnt) {
    int e = blockIdx.x * 256 + threadIdx.x;
    if (e >= Etot) return;
    int s, d;
    esd(src, dst, E, e, s, d);
    atomicAdd(&cnt[d], 1);
}

__global__ void k_scan1(const int* __restrict__ in, int* __restrict__ out, int* __restrict__ bsum,
                        int n) {
    __shared__ int tmp[256];
    int t = threadIdx.x;
    int gid = blockIdx.x * 256 + t;
    int v = gid < n ? in[gid] : 0;
    tmp[t] = v;
    __syncthreads();
    for (int off = 1; off < 256; off <<= 1) {
        int u = (t >= off) ? tmp[t - off] : 0;
        __syncthreads();
        tmp[t] += u;
        __syncthreads();
    }
    if (gid < n) out[gid] = tmp[t] - v;
    if (t == 255) bsum[blockIdx.x] = tmp[255];
}

// parallel scan of block sums (single block, chunked)
__global__ void k_scan2(int* __restrict__ bsum, int nb) {
    __shared__ int tmp[256];
    __shared__ int carry;
    int t = threadIdx.x;
    if (t == 0) carry = 0;
    __syncthreads();
    for (int base = 0; base < nb; base += 256) {
        int i = base + t;
        int v = (i < nb) ? bsum[i] : 0;
        tmp[t] = v;
        __syncthreads();
        for (int off = 1; off < 256; off <<= 1) {
            int u = (t >= off) ? tmp[t - off] : 0;
            __syncthreads();
            tmp[t] += u;
            __syncthreads();
        }
        if (i < nb) bsum[i] = tmp[t] - v + carry;
        __syncthreads();
        if (t == 0) carry += tmp[255];
        __syncthreads();
    }
}

__global__ void k_scan3(int* __restrict__ out, const int* __restrict__ bsum, int n, int Etot,
                        int* __restrict__ rp_last) {
    int gid = blockIdx.x * 256 + threadIdx.x;
    if (gid < n) out[gid] += bsum[blockIdx.x];
    if (gid == 0) rp_last[0] = Etot;
}

__global__ void k_scatter(const int* __restrict__ src, const int* __restrict__ dst, int E, int Etot,
                          int* __restrict__ cur, int* __restrict__ csrc) {
    int e = blockIdx.x * 256 + threadIdx.x;
    if (e >= Etot) return;
    int s, d;
    esd(src, dst, E, e, s, d);
    int pos = atomicAdd(&cur[d], 1);
    csrc[pos] = s;
}

// ---------------- tiled GEMM: P16[n, 0..390) = x @ W1[:, colbase+0..390) (fp16 out) ----------------
__global__ void k_gemm_w1(const float* __restrict__ x, const float* __restrict__ W1,
                          int colbase, __half* __restrict__ out16, int N) {
    __shared__ __align__(16) float xs[32][80];
    int n0 = blockIdx.x * 32;
    for (int i = threadIdx.x; i < 32 * 80; i += 256) {
        int r = i / 80, k = i - r * 80;
        int n = n0 + r;
        xs[r][k] = (k < F_IN && n < N) ? x[(size_t)n * F_IN + k] : 0.f;
    }
    __syncthreads();
    int ci = threadIdx.x & 127;
    int rh = (threadIdx.x >> 7) * 16;
    int cp = blockIdx.y * 128 + ci;
    if (2 * cp >= 390) return;
    const float* w0p = W1 + colbase + 2 * cp;
    for (int nc = rh; nc < rh + 16; nc += 8) {
        float a0[8] = {}, a1[8] = {};
        for (int k = 0; k < 76; k += 4) {
            float2 wa = *(const float2*)&w0p[(k + 0) * C1];
            float2 wb = *(const float2*)&w0p[(k + 1) * C1];
            float2 wc = *(const float2*)&w0p[(k + 2) * C1];
            float2 wd = *(const float2*)&w0p[(k + 3) * C1];
#pragma unroll
            for (int r = 0; r < 8; r++) {
                float4 xv = *(const float4*)&xs[nc + r][k];
                a0[r] = fmaf(xv.x, wa.x, a0[r]); a1[r] = fmaf(xv.x, wa.y, a1[r]);
                a0[r] = fmaf(xv.y, wb.x, a0[r]); a1[r] = fmaf(xv.y, wb.y, a1[r]);
                a0[r] = fmaf(xv.z, wc.x, a0[r]); a1[r] = fmaf(xv.z, wc.y, a1[r]);
                a0[r] = fmaf(xv.w, wd.x, a0[r]); a1[r] = fmaf(xv.w, wd.y, a1[r]);
            }
        }
        {
            float2 wa = *(const float2*)&w0p[76 * C1];
            float2 wb = *(const float2*)&w0p[77 * C1];
#pragma unroll
            for (int r = 0; r < 8; r++) {
                float4 xv = *(const float4*)&xs[nc + r][76];
                a0[r] = fmaf(xv.x, wa.x, a0[r]); a1[r] = fmaf(xv.x, wa.y, a1[r]);
                a0[r] = fmaf(xv.y, wb.x, a0[r]); a1[r] = fmaf(xv.y, wb.y, a1[r]);
            }
        }
#pragma unroll
        for (int r = 0; r < 8; r++) {
            int n = n0 + nc + r;
            if (n < N) {
                *(__half2*)&out16[(size_t)n * 390 + 2 * cp] = __floats2half2_rn(a0[r], a1[r]);
            }
        }
    }
}

// es/ed for 5 heads from fp16 P, padded layout [n*8 + hl]
__global__ void k_coef5(const __half* __restrict__ h16, const float* __restrict__ a1s,
                        const float* __restrict__ a1d, int hbase, float* __restrict__ es5,
                        float* __restrict__ ed5, int N) {
    int idx = blockIdx.x * 256 + threadIdx.x;
    if (idx >= N * 5) return;
    int hl = idx % 5, n = idx / 5;
    const __half2* hp2 = (const __half2*)(h16 + (size_t)n * 390 + hl * 78);
    const float* asp = a1s + (size_t)(hbase + hl) * 78;
    const float* adp = a1d + (size_t)(hbase + hl) * 78;
    float s = 0.f, d = 0.f;
#pragma unroll 4
    for (int j = 0; j < 39; j++) {
        float2 f = __half22float2(hp2[j]);
        s = fmaf(f.x, asp[2 * j], s);
        d = fmaf(f.x, adp[2 * j], d);
        s = fmaf(f.y, asp[2 * j + 1], s);
        d = fmaf(f.y, adp[2 * j + 1], d);
    }
    es5[(size_t)n * 8 + hl] = s;
    ed5[(size_t)n * 8 + hl] = d;
}

__global__ void k_coef1(const float* __restrict__ h, const float* __restrict__ as2,
                        const float* __restrict__ ad2, float* __restrict__ es,
                        float* __restrict__ ed, int N) {
    int n = blockIdx.x * 256 + threadIdx.x;
    if (n >= N) return;
    const float* hp = h + (size_t)n * F2;
    float s = 0.f, d = 0.f;
    for (int f = 0; f < F2; f++) {
        float v = hp[f];
        s = fmaf(v, as2[f], s);
        d = fmaf(v, ad2[f], d);
    }
    es[n] = s;
    ed[n] = d;
}

// ---------------- fused 5-head GAT: softmax + aggregate + elu -> fp16 Q ----------------
__global__ void k_gat5(const int* __restrict__ rp, const int* __restrict__ csrc,
                       const float* __restrict__ es5, const float* __restrict__ ed5,
                       const __half* __restrict__ h16, const float* __restrict__ bias,
                       __half* __restrict__ out16, int N) {
    int node = blockIdx.x * 4 + (threadIdx.x >> 6);
    if (node >= N) return;
    int lane = threadIdx.x & 63;
    int beg = rp[node], end = rp[node + 1];
    int deg = end - beg;

    float edn[5];
    {
        float4 e4 = *(const float4*)&ed5[(size_t)node * 8];
        edn[0] = e4.x; edn[1] = e4.y; edn[2] = e4.z; edn[3] = e4.w;
        edn[4] = ed5[(size_t)node * 8 + 4];
    }

    float acc[7] = {0.f, 0.f, 0.f, 0.f, 0.f, 0.f, 0.f};

#define ACC_STEP(sb, A0, A1, A2, A3, A4)                                              \
    {                                                                                 \
        const __half* hp = h16 + (size_t)(sb) * 390;                                  \
        acc[0] = fmaf(A0, __half2float(hp[lane]), acc[0]);                            \
        { float a = (64 + lane < 78) ? A0 : A1;                                       \
          acc[1] = fmaf(a, __half2float(hp[64 + lane]), acc[1]); }                    \
        { float a = (128 + lane < 156) ? A1 : A2;                                     \
          acc[2] = fmaf(a, __half2float(hp[128 + lane]), acc[2]); }                   \
        { float a = (192 + lane < 234) ? A2 : A3;                                     \
          acc[3] = fmaf(a, __half2float(hp[192 + lane]), acc[3]); }                   \
        { float a = (256 + lane < 312) ? A3 : A4;                                     \
          acc[4] = fmaf(a, __half2float(hp[256 + lane]), acc[4]); }                   \
        acc[5] = fmaf(A4, __half2float(hp[320 + lane]), acc[5]);                      \
        if (lane < 6) acc[6] = fmaf(A4, __half2float(hp[384 + lane]), acc[6]);        \
    }

    if (deg <= 64) {
        // ---- fast path: one chunk, plain butterfly softmax ----
        bool act = lane < deg;
        int s = act ? csrc[beg + lane] : 0;
        float v[5];
        if (act) {
            float4 q4 = *(const float4*)&es5[(size_t)s * 8];
            float q4b = es5[(size_t)s * 8 + 4];
            v[0] = q4.x + edn[0]; v[1] = q4.y + edn[1]; v[2] = q4.z + edn[2];
            v[3] = q4.w + edn[3]; v[4] = q4b + edn[4];
#pragma unroll
            for (int hl = 0; hl < 5; hl++) v[hl] = v[hl] >= 0.f ? v[hl] : 0.2f * v[hl];
        } else {
#pragma unroll
            for (int hl = 0; hl < 5; hl++) v[hl] = -3.0e38f;
        }
        float m[5];
#pragma unroll
        for (int hl = 0; hl < 5; hl++) m[hl] = v[hl];
#pragma unroll
        for (int off = 32; off; off >>= 1) {
#pragma unroll
            for (int hl = 0; hl < 5; hl++) m[hl] = fmaxf(m[hl], __shfl_xor(m[hl], off));
        }
        float p[5], ss[5];
#pragma unroll
        for (int hl = 0; hl < 5; hl++) {
            p[hl] = act ? __expf(v[hl] - m[hl]) : 0.f;
            ss[hl] = p[hl];
        }
#pragma unroll
        for (int off = 32; off; off >>= 1) {
#pragma unroll
            for (int hl = 0; hl < 5; hl++) ss[hl] += __shfl_xor(ss[hl], off);
        }
#pragma unroll
        for (int hl = 0; hl < 5; hl++) p[hl] *= 1.f / ss[hl];

        for (int i = 0; i < deg; i++) {
            int sb = __shfl(s, i);
            float a0 = __shfl(p[0], i), a1 = __shfl(p[1], i), a2 = __shfl(p[2], i),
                  a3 = __shfl(p[3], i), a4 = __shfl(p[4], i);
            ACC_STEP(sb, a0, a1, a2, a3, a4);
        }
    } else {
        // ---- general path: online softmax over chunks ----
        float m[5], ss[5];
#pragma unroll
        for (int hl = 0; hl < 5; hl++) { m[hl] = -3.0e38f; ss[hl] = 0.f; }
        for (int cb = beg; cb < end; cb += 64) {
            int e = cb + lane;
            bool act = e < end;
            int s = act ? csrc[e] : 0;
            float v[5];
            if (act) {
                float4 q4 = *(const float4*)&es5[(size_t)s * 8];
                float q4b = es5[(size_t)s * 8 + 4];
                v[0] = q4.x + edn[0]; v[1] = q4.y + edn[1]; v[2] = q4.z + edn[2];
                v[3] = q4.w + edn[3]; v[4] = q4b + edn[4];
#pragma unroll
                for (int hl = 0; hl < 5; hl++) v[hl] = v[hl] >= 0.f ? v[hl] : 0.2f * v[hl];
            } else {
#pragma unroll
                for (int hl = 0; hl < 5; hl++) v[hl] = -3.0e38f;
            }
#pragma unroll
            for (int hl = 0; hl < 5; hl++) {
                float vv = v[hl];
                if (vv > m[hl]) { ss[hl] = ss[hl] * __expf(m[hl] - vv) + 1.f; m[hl] = vv; }
                else ss[hl] += __expf(vv - m[hl]);
            }
        }
#pragma unroll
        for (int off = 32; off; off >>= 1) {
#pragma unroll
            for (int hl = 0; hl < 5; hl++) {
                float om = __shfl_xor(m[hl], off), os = __shfl_xor(ss[hl], off);
                float nm = fmaxf(m[hl], om);
                ss[hl] = ss[hl] * __expf(m[hl] - nm) + os * __expf(om - nm);
                m[hl] = nm;
            }
        }
        float inv[5];
#pragma unroll
        for (int hl = 0; hl < 5; hl++) inv[hl] = 1.f / ss[hl];

        for (int cb = beg; cb < end; cb += 64) {
            int cnt = min(64, end - cb);
            int e = cb + lane;
            bool act = e < end;
            int s = act ? csrc[e] : 0;
            float p[5];
            if (act) {
                float4 q4 = *(const float4*)&es5[(size_t)s * 8];
                float q4b = es5[(size_t)s * 8 + 4];
                float v[5];
                v[0] = q4.x + edn[0]; v[1] = q4.y + edn[1]; v[2] = q4.z + edn[2];
                v[3] = q4.w + edn[3]; v[4] = q4b + edn[4];
#pragma unroll
                for (int hl = 0; hl < 5; hl++) {
                    float vv = v[hl] >= 0.f ? v[hl] : 0.2f * v[hl];
                    p[hl] = __expf(vv - m[hl]) * inv[hl];
                }
            } else {
#pragma unroll
                for (int hl = 0; hl < 5; hl++) p[hl] = 0.f;
            }
            for (int i = 0; i < cnt; i++) {
                int sb = __shfl(s, i);
                float a0 = __shfl(p[0], i), a1 = __shfl(p[1], i), a2 = __shfl(p[2], i),
                      a3 = __shfl(p[3], i), a4 = __shfl(p[4], i);
                ACC_STEP(sb, a0, a1, a2, a3, a4);
            }
        }
    }
#undef ACC_STEP

    __half* op = out16 + (size_t)node * 390;
#pragma unroll
    for (int j = 0; j < 6; j++) {
        int c = j * 64 + lane;
        float t = acc[j] + bias[c];
        op[c] = __float2half_rn(t > 0.f ? t : expm1f(t));
    }
    if (lane < 6) {
        int c = 384 + lane;
        float t = acc[6] + bias[c];
        op[c] = __float2half_rn(t > 0.f ? t : expm1f(t));
    }
}

// ---------------- layer-2 GAT (1 head, 128 ch) + fused relu/max-pool; fp16 h gather ----------------
__global__ void k_gatP(const int* __restrict__ rp, const int* __restrict__ csrc,
                       const float* __restrict__ es, const float* __restrict__ ed,
                       const __half2* __restrict__ h216, const float* __restrict__ b2,
                       const int* __restrict__ batch, unsigned* __restrict__ gb, int N) {
    int node = blockIdx.x * 4 + (threadIdx.x >> 6);
    if (node >= N) return;
    int lane = threadIdx.x & 63;
    int beg = rp[node], end = rp[node + 1];
    int deg = end - beg;
    float edn = ed[node];

    float acc0 = 0.f, acc1 = 0.f;

    if (deg <= 64) {
        bool act = lane < deg;
        int s = act ? csrc[beg + lane] : 0;
        float v = -3.0e38f;
        if (act) {
            v = es[s] + edn;
            v = v >= 0.f ? v : 0.2f * v;
        }
        float m = v;
#pragma unroll
        for (int off = 32; off; off >>= 1) m = fmaxf(m, __shfl_xor(m, off));
        float p = act ? __expf(v - m) : 0.f;
        float ss = p;
#pragma unroll
        for (int off = 32; off; off >>= 1) ss += __shfl_xor(ss, off);
        p *= 1.f / ss;

        for (int i = 0; i < deg; i++) {
            int sb = __shfl(s, i);
            float a = __shfl(p, i);
            float2 f = __half22float2(h216[(size_t)sb * 64 + lane]);
            acc0 = fmaf(a, f.x, acc0);
            acc1 = fmaf(a, f.y, acc1);
        }
    } else {
        float m = -3.0e38f, ss = 0.f;
        for (int cb = beg; cb < end; cb += 64) {
            int e = cb + lane;
            bool act = e < end;
            int s = act ? csrc[e] : 0;
            float v = -3.0e38f;
            if (act) {
                v = es[s] + edn;
                v = v >= 0.f ? v : 0.2f * v;
            }
            if (v > m) { ss = ss * __expf(m - v) + 1.f; m = v; }
            else ss += __expf(v - m);
        }
#pragma unroll
        for (int off = 32; off; off >>= 1) {
            float om = __shfl_xor(m, off), os = __shfl_xor(ss, off);
            float nm = fmaxf(m, om);
            ss = ss * __expf(m - nm) + os * __expf(om - nm);
            m = nm;
        }
        float inv = 1.f / ss;
        for (int cb = beg; cb < end; cb += 64) {
            int cnt = min(64, end - cb);
            int e = cb + lane;
            bool act = e < end;
            int s = act ? csrc[e] : 0;
            float p = 0.f;
            if (act) {
                float v = es[s] + edn;
                v = v >= 0.f ? v : 0.2f * v;
                p = __expf(v - m) * inv;
            }
            for (int i = 0; i < cnt; i++) {
                int sb = __shfl(s, i);
                float a = __shfl(p, i);
                float2 f = __half22float2(h216[(size_t)sb * 64 + lane]);
                acc0 = fmaf(a, f.x, acc0);
                acc1 = fmaf(a, f.y, acc1);
            }
        }
    }

    unsigned* gp = gb + (size_t)batch[node] * F2;
    float t0 = fmaxf(acc0 + b2[2 * lane], 0.f);
    atomicMax(&gp[2 * lane], __float_as_uint(t0));
    float t1 = fmaxf(acc1 + b2[2 * lane + 1], 0.f);
    atomicMax(&gp[2 * lane + 1], __float_as_uint(t1));
}

// ---------------- h2 += Q16(5 heads) @ W2-slice; FINAL also writes fp16 copy ----------------
template <bool FINAL>
__global__ void k_gemm_acc5(const __half* __restrict__ q16, const float* __restrict__ W2,
                            int kbase, float* __restrict__ h2, __half2* __restrict__ h216,
                            int N) {
    __shared__ __align__(16) float as_[32][80];
    int n0 = blockIdx.x * 32;
    int ci = threadIdx.x & 63;
    int r0 = (threadIdx.x >> 6) * 8;
    float a0[8] = {}, a1[8] = {};
    const __half2* q2 = (const __half2*)q16;
    for (int hl = 0; hl < 5; hl++) {
        __syncthreads();
        for (int i = threadIdx.x; i < 32 * 39; i += 256) {
            int r = i / 39, jj = i - r * 39;
            int n = n0 + r;
            float2 f = {0.f, 0.f};
            if (n < N) f = __half22float2(q2[(size_t)n * 195 + hl * 39 + jj]);
            as_[r][2 * jj] = f.x;
            as_[r][2 * jj + 1] = f.y;
        }
        if (threadIdx.x < 32) {
            as_[threadIdx.x][78] = 0.f;
            as_[threadIdx.x][79] = 0.f;
        }
        __syncthreads();
        const float* wp = W2 + (size_t)(kbase + hl * 78) * F2 + 2 * ci;
        for (int k = 0; k < 76; k += 4) {
            float2 wa = *(const float2*)&wp[(k + 0) * F2];
            float2 wb = *(const float2*)&wp[(k + 1) * F2];
            float2 wc = *(const float2*)&wp[(k + 2) * F2];
            float2 wd = *(const float2*)&wp[(k + 3) * F2];
#pragma unroll
            for (int r = 0; r < 8; r++) {
                float4 xv = *(const float4*)&as_[r0 + r][k];
                a0[r] = fmaf(xv.x, wa.x, a0[r]); a1[r] = fmaf(xv.x, wa.y, a1[r]);
                a0[r] = fmaf(xv.y, wb.x, a0[r]); a1[r] = fmaf(xv.y, wb.y, a1[r]);
                a0[r] = fmaf(xv.z, wc.x, a0[r]); a1[r] = fmaf(xv.z, wc.y, a1[r]);
                a0[r] = fmaf(xv.w, wd.x, a0[r]); a1[r] = fmaf(xv.w, wd.y, a1[r]);
            }
        }
        {
            float2 wa = *(const float2*)&wp[76 * F2];
            float2 wb = *(const float2*)&wp[77 * F2];
#pragma unroll
            for (int r = 0; r < 8; r++) {
                float4 xv = *(const float4*)&as_[r0 + r][76];
                a0[r] = fmaf(xv.x, wa.x, a0[r]); a1[r] = fmaf(xv.x, wa.y, a1[r]);
                a0[r] = fmaf(xv.y, wb.x, a0[r]); a1[r] = fmaf(xv.y, wb.y, a1[r]);
            }
        }
    }
#pragma unroll
    for (int r = 0; r < 8; r++) {
        int n = n0 + r0 + r;
        if (n < N) {
            float2* h2p = (float2*)&h2[(size_t)n * F2 + 2 * ci];
            float2 cur = *h2p;
            cur.x += a0[r];
            cur.y += a1[r];
            *h2p = cur;
            if (FINAL) h216[(size_t)n * 64 + ci] = __floats2half2_rn(cur.x, cur.y);
        }
    }
}

// ---------------- head ----------------
__global__ void k_head_g(const unsigned* __restrict__ gbits, const float* __restrict__ Wg,
                         const float* __restrict__ bg, float* __restrict__ xc) {
    int b = blockIdx.x, c = threadIdx.x;
    __shared__ float srow[F2];
    srow[c] = __uint_as_float(gbits[(size_t)b * F2 + c]);
    __syncthreads();
    float acc = bg[c];
    for (int k = 0; k < F2; k++) acc = fmaf(srow[k], Wg[k * F2 + c], acc);
    xc[(size_t)b * 256 + c] = fmaxf(acc, 0.f);
}

__global__ void k_head_xt(const float* __restrict__ te, const float* __restrict__ Wxt,
                          const float* __restrict__ bxt, const float* __restrict__ gamma,
                          const float* __restrict__ beta, const float* __restrict__ rmean,
                          const float* __restrict__ rvar, float* __restrict__ xc) {
    int b = blockIdx.x, c = threadIdx.x;
    __shared__ float srow[EMB];
    for (int k = c; k < EMB; k += 128) srow[k] = te[(size_t)b * EMB + k];
    __syncthreads();
    float acc = bxt[c];
    for (int k = 0; k < EMB; k++) acc = fmaf(srow[k], Wxt[k * F2 + c], acc);
    acc = (acc - rmean[c]) * rsqrtf(rvar[c] + 1e-5f) * gamma[c] + beta[c];
    xc[(size_t)b * 256 + 128 + c] = fmaxf(acc, 0.f);
}

__global__ void k_head_f1(const float* __restrict__ xc, const float* __restrict__ W,
                          const float* __restrict__ bias, float* __restrict__ o) {
    int b = blockIdx.x;
    __shared__ float srow[256];
    srow[threadIdx.x] = xc[(size_t)b * 256 + threadIdx.x];
    __syncthreads();
    for (int col = threadIdx.x; col < 1024; col += 256) {
        float acc = bias[col];
        for (int k = 0; k < 256; k++) acc = fmaf(srow[k], W[k * 1024 + col], acc);
        o[(size_t)b * 1024 + col] = fmaxf(acc, 0.f);
    }
}

__global__ void k_head_f2(const float* __restrict__ in, const float* __restrict__ W,
                          const float* __restrict__ bias, float* __restrict__ o) {
    int b = blockIdx.x;
    int col = threadIdx.x;
    __shared__ float srow[1024];
    for (int k = col; k < 1024; k += 256) srow[k] = in[(size_t)b * 1024 + k];
    __syncthreads();
    float acc = bias[col];
    for (int k = 0; k < 1024; k++) acc = fmaf(srow[k], W[k * 256 + col], acc);
    o[(size_t)b * 256 + col] = fmaxf(acc, 0.f);
}

__global__ void k_head_out(const float* __restrict__ in, const float* __restrict__ Wo,
                           const float* __restrict__ bo, float* __restrict__ out) {
    int b = blockIdx.x;
    float acc = 0.f;
    for (int k = threadIdx.x; k < 256; k += 64) acc = fmaf(in[(size_t)b * 256 + k], Wo[k], acc);
    for (int off = 32; off; off >>= 1) acc += __shfl_down(acc, off);
    if (threadIdx.x == 0) out[b] = acc + bo[0];
}

extern "C" void kernel_launch(void* const* d_in, const int* in_sizes, int n_in,
                              void* d_out, int out_size, void* d_ws, size_t ws_size,
                              hipStream_t stream) {
    const float* x     = (const float*)d_in[0];
    const int*   ei    = (const int*)d_in[1];
    const int*   batch = (const int*)d_in[2];
    const float* te    = (const float*)d_in[3];
    const float* W1    = (const float*)d_in[4];
    const float* a1s   = (const float*)d_in[5];
    const float* a1d   = (const float*)d_in[6];
    const float* b1    = (const float*)d_in[7];
    const float* W2    = (const float*)d_in[8];
    const float* a2s   = (const float*)d_in[9];
    const float* a2d   = (const float*)d_in[10];
    const float* b2    = (const float*)d_in[11];
    const float* Wg    = (const float*)d_in[12];
    const float* bg    = (const float*)d_in[13];
    const float* Wxt   = (const float*)d_in[14];
    const float* bxt   = (const float*)d_in[15];
    const float* gamma = (const float*)d_in[16];
    const float* beta  = (const float*)d_in[17];
    const float* rmean = (const float*)d_in[18];
    const float* rvar  = (const float*)d_in[19];
    const float* Wf1   = (const float*)d_in[20];
    const float* bf1   = (const float*)d_in[21];
    const float* Wf2   = (const float*)d_in[22];
    const float* bf2   = (const float*)d_in[23];
    const float* Wo    = (const float*)d_in[24];
    const float* bo    = (const float*)d_in[25];

    const int N = in_sizes[0] / F_IN;
    const int E = in_sizes[1] / 2;
    const int B = in_sizes[3] / EMB;
    const int Etot = E + N;
    const int* src = ei;
    const int* dst = ei + E;

    char* p = (char*)d_ws;
    auto alloc = [&](size_t bytes) -> void* {
        void* r = p;
        p += (bytes + 255) & ~(size_t)255;
        return r;
    };
    __half*   P16  = (__half*)alloc((size_t)N * 390 * 2);   // 39 MB
    __half*   Q16  = (__half*)alloc((size_t)N * 390 * 2);   // 39 MB
    float*    h2   = (float*)alloc((size_t)N * F2 * 4);     // 25.6 MB
    __half2*  h216 = (__half2*)alloc((size_t)N * F2 * 2);   // 12.8 MB
    float*    es5  = (float*)alloc((size_t)N * 8 * 4);
    float*    ed5  = (float*)alloc((size_t)N * 8 * 4);
    int*      cnt  = (int*)alloc((size_t)N * 4);
    int*      rp   = (int*)alloc((size_t)(N + 1) * 4);
    int*      cur  = (int*)alloc((size_t)N * 4);
    int*      csrc = (int*)alloc((size_t)Etot * 4);
    int*      bsum = (int*)alloc((size_t)1024 * 4);
    unsigned* gb   = (unsigned*)alloc((size_t)B * F2 * 4);
    float*    xc   = (float*)alloc((size_t)B * 256 * 4);
    float*    f1o  = (float*)alloc((size_t)B * 1024 * 4);
    float*    f2o  = (float*)alloc((size_t)B * 256 * 4);

    auto gsz = [](long long t) { return (int)((t + 255) / 256); };
    const int nb = gsz(N);
    const int nwave = (N + 3) / 4;

    // ---- CSR build ----
    hipMemsetAsync(cnt, 0, (size_t)N * 4, stream);
    k_count<<<gsz(Etot), 256, 0, stream>>>(src, dst, E, Etot, cnt);
    k_scan1<<<nb, 256, 0, stream>>>(cnt, rp, bsum, N);
    k_scan2<<<1, 256, 0, stream>>>(bsum, nb);
    k_scan3<<<nb, 256, 0, stream>>>(rp, bsum, N, Etot, rp + N);
    hipMemcpyAsync(cur, rp, (size_t)N * 4, hipMemcpyDeviceToDevice, stream);
    k_scatter<<<gsz(Etot), 256, 0, stream>>>(src, dst, E, Etot, cur, csrc);

    hipMemsetAsync(h2, 0, (size_t)N * F2 * 4, stream);
    hipMemsetAsync(gb, 0, (size_t)B * F2 * 4, stream);

    // ---- GAT layer 1: 2 groups of 5 heads ----
    for (int g = 0; g < 2; g++) {
        k_gemm_w1<<<dim3((N + 31) / 32, 2), 256, 0, stream>>>(x, W1, g * 390, P16, N);
        k_coef5<<<gsz((long long)N * 5), 256, 0, stream>>>(P16, a1s, a1d, g * 5, es5, ed5, N);
        k_gat5<<<nwave, 256, 0, stream>>>(rp, csrc, es5, ed5, P16, b1 + (size_t)g * 390, Q16, N);
        if (g == 0)
            k_gemm_acc5<false><<<(N + 31) / 32, 256, 0, stream>>>(Q16, W2, 0, h2, h216, N);
        else
            k_gemm_acc5<true><<<(N + 31) / 32, 256, 0, stream>>>(Q16, W2, 390, h2, h216, N);
    }

    // ---- GAT layer 2 (1 head, 128 ch) + fused pool ----
    k_coef1<<<nb, 256, 0, stream>>>(h2, a2s, a2d, es5, ed5, N);
    k_gatP<<<nwave, 256, 0, stream>>>(rp, csrc, es5, ed5, h216, b2, batch, gb, N);

    // ---- head ----
    k_head_g<<<B, 128, 0, stream>>>(gb, Wg, bg, xc);
    k_head_xt<<<B, 128, 0, stream>>>(te, Wxt, bxt, gamma, beta, rmean, rvar, xc);
    k_head_f1<<<B, 256, 0, stream>>>(xc, Wf1, bf1, f1o);
    k_head_f2<<<B, 256, 0, stream>>>(f1o, Wf2, bf2, f2o);
    k_head_out<<<B, 64, 0, stream>>>(f2o, Wo, bo, (float*)d_out);
}

// Round 7
// 492.571 us; speedup vs baseline: 9.6328x; 1.6434x over previous
//
#include <hip/hip_runtime.h>
#include <hip/hip_fp16.h>
#include <math.h>

static constexpr int F2 = 128, EMB = 320;

typedef _Float16 h8v __attribute__((ext_vector_type(8)));
typedef float f4v __attribute__((ext_vector_type(4)));

__device__ __forceinline__ void esd(const int* src, const int* dst, int E, int e, int& s, int& d) {
    if (e < E) { s = src[e]; d = dst[e]; }
    else       { s = e - E; d = s; }
}

// ---------------- CSR build ----------------
__global__ void k_count(const int* __restrict__ src, const int* __restrict__ dst, int E, int Etot,
                        int* __restrict__ cnt) {
    int e = blockIdx.x * 256 + threadIdx.x;
    if (e >= Etot) return;
    int s, d;
    esd(src, dst, E, e, s, d);
    atomicAdd(&cnt[d], 1);
}

__global__ void k_scan1(const int* __restrict__ in, int* __restrict__ out, int* __restrict__ bsum,
                        int n) {
    __shared__ int tmp[256];
    int t = threadIdx.x;
    int gid = blockIdx.x * 256 + t;
    int v = gid < n ? in[gid] : 0;
    tmp[t] = v;
    __syncthreads();
    for (int off = 1; off < 256; off <<= 1) {
        int u = (t >= off) ? tmp[t - off] : 0;
        __syncthreads();
        tmp[t] += u;
        __syncthreads();
    }
    if (gid < n) out[gid] = tmp[t] - v;
    if (t == 255) bsum[blockIdx.x] = tmp[255];
}

__global__ void k_scan2(int* __restrict__ bsum, int nb) {
    __shared__ int tmp[256];
    __shared__ int carry;
    int t = threadIdx.x;
    if (t == 0) carry = 0;
    __syncthreads();
    for (int base = 0; base < nb; base += 256) {
        int i = base + t;
        int v = (i < nb) ? bsum[i] : 0;
        tmp[t] = v;
        __syncthreads();
        for (int off = 1; off < 256; off <<= 1) {
            int u = (t >= off) ? tmp[t - off] : 0;
            __syncthreads();
            tmp[t] += u;
            __syncthreads();
        }
        if (i < nb) bsum[i] = tmp[t] - v + carry;
        __syncthreads();
        if (t == 0) carry += tmp[255];
        __syncthreads();
    }
}

__global__ void k_scan3(int* __restrict__ out, const int* __restrict__ bsum, int n, int Etot,
                        int* __restrict__ rp_last) {
    int gid = blockIdx.x * 256 + threadIdx.x;
    if (gid < n) out[gid] += bsum[blockIdx.x];
    if (gid == 0) rp_last[0] = Etot;
}

__global__ void k_scatter(const int* __restrict__ src, const int* __restrict__ dst, int E, int Etot,
                          int* __restrict__ cur, int* __restrict__ csrc) {
    int e = blockIdx.x * 256 + threadIdx.x;
    if (e >= Etot) return;
    int s, d;
    esd(src, dst, E, e, s, d);
    int pos = atomicAdd(&cur[d], 1);
    csrc[pos] = s;
}

// ---------------- prep: fp16/transposed weights, x16, attention weight vectors ----------------
// W1T [10][80][96]: W1T[h][c][k] = W1[k][h*78+c]
__global__ void k_prep_w1t(const float* __restrict__ W1, __half* __restrict__ W1T) {
    int idx = blockIdx.x * 256 + threadIdx.x;
    if (idx >= 10 * 80 * 96) return;
    int h = idx / (80 * 96), r = idx % (80 * 96), c = r / 96, k = r % 96;
    float v = (c < 78 && k < 78) ? W1[(size_t)k * 780 + h * 78 + c] : 0.f;
    W1T[idx] = __float2half(v);
}

// wes/wed [10][80]: wes[h][k] = sum_f W1[k][h*78+f] * a1s[h][f]
__global__ void k_prep_wes(const float* __restrict__ W1, const float* __restrict__ a1s,
                           const float* __restrict__ a1d, float* __restrict__ wes,
                           float* __restrict__ wed) {
    int idx = blockIdx.x * 256 + threadIdx.x;
    if (idx >= 10 * 80) return;
    int h = idx / 80, k = idx % 80;
    float s = 0.f, d = 0.f;
    if (k < 78) {
        for (int f = 0; f < 78; f++) {
            float w = W1[(size_t)k * 780 + h * 78 + f];
            s = fmaf(w, a1s[h * 78 + f], s);
            d = fmaf(w, a1d[h * 78 + f], d);
        }
    }
    wes[idx] = s;
    wed[idx] = d;
}

// W2T [128][800]: W2T[c][k] = W2[k][c]
__global__ void k_prep_w2t(const float* __restrict__ W2, __half* __restrict__ W2T) {
    int idx = blockIdx.x * 256 + threadIdx.x;
    if (idx >= 128 * 800) return;
    int c = idx / 800, k = idx % 800;
    float v = (k < 780) ? W2[(size_t)k * 128 + c] : 0.f;
    W2T[idx] = __float2half(v);
}

// x16 [N][96]
__global__ void k_prep_x16(const float* __restrict__ x, __half* __restrict__ x16, int N) {
    int idx = blockIdx.x * 256 + threadIdx.x;
    if (idx >= N * 96) return;
    int n = idx / 96, k = idx - n * 96;
    x16[idx] = __float2half(k < 78 ? x[(size_t)n * 78 + k] : 0.f);
}

// es/ed for all 10 heads directly from x: esg [2][N][8], edg [2][N][8]
__global__ void k_coefx(const float* __restrict__ x, const float* __restrict__ wes,
                        const float* __restrict__ wed, float* __restrict__ esg,
                        float* __restrict__ edg, int N) {
    int n = blockIdx.x * 256 + threadIdx.x;
    if (n >= N) return;
    float es[10] = {}, ed[10] = {};
    const float* xr = x + (size_t)n * 78;
    for (int k = 0; k < 78; k++) {
        float xv = xr[k];
#pragma unroll
        for (int h = 0; h < 10; h++) {
            es[h] = fmaf(xv, wes[h * 80 + k], es[h]);
            ed[h] = fmaf(xv, wed[h * 80 + k], ed[h]);
        }
    }
#pragma unroll
    for (int g = 0; g < 2; g++) {
#pragma unroll
        for (int h = 0; h < 5; h++) {
            esg[((size_t)g * N + n) * 8 + h] = es[g * 5 + h];
            edg[((size_t)g * N + n) * 8 + h] = ed[g * 5 + h];
        }
    }
}

// ---------------- fused 5-head GAT on x: softmax + aggregate x -> xagg [N][5][96] ----------------
__global__ void k_gatx5(const int* __restrict__ rp, const int* __restrict__ csrc,
                        const float* __restrict__ es, const float* __restrict__ ed,
                        const __half* __restrict__ x16, __half* __restrict__ xagg, int N) {
    int node = blockIdx.x * 4 + (threadIdx.x >> 6);
    if (node >= N) return;
    int lane = threadIdx.x & 63;
    int beg = rp[node], end = rp[node + 1];
    int deg = end - beg;

    float edn[5];
    {
        const float* ep = ed + (size_t)node * 8;
        float4 e4 = *(const float4*)ep;
        edn[0] = e4.x; edn[1] = e4.y; edn[2] = e4.z; edn[3] = e4.w; edn[4] = ep[4];
    }

    float acc[5][2] = {};

    if (deg <= 64) {
        bool act = lane < deg;
        int s = act ? csrc[beg + lane] : 0;
        float v[5];
        if (act) {
            const float* sp = es + (size_t)s * 8;
            float4 q = *(const float4*)sp;
            float q4 = sp[4];
            v[0] = q.x + edn[0]; v[1] = q.y + edn[1]; v[2] = q.z + edn[2];
            v[3] = q.w + edn[3]; v[4] = q4 + edn[4];
#pragma unroll
            for (int h = 0; h < 5; h++) v[h] = v[h] >= 0.f ? v[h] : 0.2f * v[h];
        } else {
#pragma unroll
            for (int h = 0; h < 5; h++) v[h] = -3.0e38f;
        }
        float m[5];
#pragma unroll
        for (int h = 0; h < 5; h++) m[h] = v[h];
        int start = (deg <= 16) ? 8 : 32;
        for (int off = start; off; off >>= 1) {
#pragma unroll
            for (int h = 0; h < 5; h++) m[h] = fmaxf(m[h], __shfl_xor(m[h], off));
        }
        float p[5], ss[5];
#pragma unroll
        for (int h = 0; h < 5; h++) {
            p[h] = act ? __expf(v[h] - m[h]) : 0.f;
            ss[h] = p[h];
        }
        for (int off = start; off; off >>= 1) {
#pragma unroll
            for (int h = 0; h < 5; h++) ss[h] += __shfl_xor(ss[h], off);
        }
#pragma unroll
        for (int h = 0; h < 5; h++) p[h] *= 1.f / ss[h];

        for (int i = 0; i < deg; i++) {
            int sb = __shfl(s, i);
            const __half* hp = x16 + (size_t)sb * 96;
            float xa = __half2float(hp[lane]);
            float xb = (lane < 14) ? __half2float(hp[64 + lane]) : 0.f;
            float a0 = __shfl(p[0], i), a1 = __shfl(p[1], i), a2 = __shfl(p[2], i),
                  a3 = __shfl(p[3], i), a4 = __shfl(p[4], i);
            acc[0][0] = fmaf(a0, xa, acc[0][0]); acc[0][1] = fmaf(a0, xb, acc[0][1]);
            acc[1][0] = fmaf(a1, xa, acc[1][0]); acc[1][1] = fmaf(a1, xb, acc[1][1]);
            acc[2][0] = fmaf(a2, xa, acc[2][0]); acc[2][1] = fmaf(a2, xb, acc[2][1]);
            acc[3][0] = fmaf(a3, xa, acc[3][0]); acc[3][1] = fmaf(a3, xb, acc[3][1]);
            acc[4][0] = fmaf(a4, xa, acc[4][0]); acc[4][1] = fmaf(a4, xb, acc[4][1]);
        }
    } else {
        // general path: online softmax over chunks
        float m[5], ss[5];
#pragma unroll
        for (int h = 0; h < 5; h++) { m[h] = -3.0e38f; ss[h] = 0.f; }
        for (int cb = beg; cb < end; cb += 64) {
            int e = cb + lane;
            bool act = e < end;
            int s = act ? csrc[e] : 0;
            float v[5];
            if (act) {
                const float* sp = es + (size_t)s * 8;
                float4 q = *(const float4*)sp;
                float q4 = sp[4];
                v[0] = q.x + edn[0]; v[1] = q.y + edn[1]; v[2] = q.z + edn[2];
                v[3] = q.w + edn[3]; v[4] = q4 + edn[4];
#pragma unroll
                for (int h = 0; h < 5; h++) v[h] = v[h] >= 0.f ? v[h] : 0.2f * v[h];
            } else {
#pragma unroll
                for (int h = 0; h < 5; h++) v[h] = -3.0e38f;
            }
#pragma unroll
            for (int h = 0; h < 5; h++) {
                float vv = v[h];
                if (vv > m[h]) { ss[h] = ss[h] * __expf(m[h] - vv) + 1.f; m[h] = vv; }
                else ss[h] += __expf(vv - m[h]);
            }
        }
#pragma unroll
        for (int off = 32; off; off >>= 1) {
#pragma unroll
            for (int h = 0; h < 5; h++) {
                float om = __shfl_xor(m[h], off), os = __shfl_xor(ss[h], off);
                float nm = fmaxf(m[h], om);
                ss[h] = ss[h] * __expf(m[h] - nm) + os * __expf(om - nm);
                m[h] = nm;
            }
        }
        float inv[5];
#pragma unroll
        for (int h = 0; h < 5; h++) inv[h] = 1.f / ss[h];

        for (int cb = beg; cb < end; cb += 64) {
            int cnt = min(64, end - cb);
            int e = cb + lane;
            bool act = e < end;
            int s = act ? csrc[e] : 0;
            float p[5];
            if (act) {
                const float* sp = es + (size_t)s * 8;
                float4 q = *(const float4*)sp;
                float q4 = sp[4];
                float v[5];
                v[0] = q.x + edn[0]; v[1] = q.y + edn[1]; v[2] = q.z + edn[2];
                v[3] = q.w + edn[3]; v[4] = q4 + edn[4];
#pragma unroll
                for (int h = 0; h < 5; h++) {
                    float vv = v[h] >= 0.f ? v[h] : 0.2f * v[h];
                    p[h] = __expf(vv - m[h]) * inv[h];
                }
            } else {
#pragma unroll
                for (int h = 0; h < 5; h++) p[h] = 0.f;
            }
            for (int i = 0; i < cnt; i++) {
                int sb = __shfl(s, i);
                const __half* hp = x16 + (size_t)sb * 96;
                float xa = __half2float(hp[lane]);
                float xb = (lane < 14) ? __half2float(hp[64 + lane]) : 0.f;
                float a0 = __shfl(p[0], i), a1 = __shfl(p[1], i), a2 = __shfl(p[2], i),
                      a3 = __shfl(p[3], i), a4 = __shfl(p[4], i);
                acc[0][0] = fmaf(a0, xa, acc[0][0]); acc[0][1] = fmaf(a0, xb, acc[0][1]);
                acc[1][0] = fmaf(a1, xa, acc[1][0]); acc[1][1] = fmaf(a1, xb, acc[1][1]);
                acc[2][0] = fmaf(a2, xa, acc[2][0]); acc[2][1] = fmaf(a2, xb, acc[2][1]);
                acc[3][0] = fmaf(a3, xa, acc[3][0]); acc[3][1] = fmaf(a3, xb, acc[3][1]);
                acc[4][0] = fmaf(a4, xa, acc[4][0]); acc[4][1] = fmaf(a4, xb, acc[4][1]);
            }
        }
    }

    __half* op = xagg + (size_t)node * 480;
#pragma unroll
    for (int h = 0; h < 5; h++) {
        __half* hp = op + h * 96;
        hp[lane] = __float2half(acc[h][0]);
        if (lane < 14) hp[64 + lane] = __float2half(acc[h][1]);
        else if (lane < 32) hp[64 + lane] = __float2half(0.f);
    }
}

// ---------------- per-head 78->78 MFMA GEMM + bias + elu -> Q [N][800] ----------------
__global__ __launch_bounds__(256) void k_gemm_hh(const __half* __restrict__ xagg,
                                                 const __half* __restrict__ W1T,
                                                 const float* __restrict__ b1,
                                                 __half* __restrict__ Q, int g, int N) {
    int wid = threadIdx.x >> 6, lane = threadIdx.x & 63;
    int by = blockIdx.y;
    int h = g * 5 + by;
    int row0 = blockIdx.x * 64 + wid * 16;
    int ar = min(row0 + (lane & 15), N - 1);
    int ko = (lane >> 4) * 8;
    f4v acc[5] = {};
    const __half* Ap = xagg + ((size_t)ar * 5 + by) * 96 + ko;
    const __half* Bb = W1T + ((size_t)h * 80 + (lane & 15)) * 96 + ko;
#pragma unroll
    for (int ks = 0; ks < 3; ks++) {
        h8v a = *(const h8v*)(Ap + ks * 32);
#pragma unroll
        for (int t = 0; t < 5; t++) {
            h8v b = *(const h8v*)(Bb + (size_t)t * 16 * 96 + ks * 32);
            acc[t] = __builtin_amdgcn_mfma_f32_16x16x32_f16(a, b, acc[t], 0, 0, 0);
        }
    }
    int col16 = lane & 15, rbase = (lane >> 4) * 4;
#pragma unroll
    for (int t = 0; t < 5; t++) {
        int c = t * 16 + col16;
        if (c >= 78) continue;
        float bias = b1[h * 78 + c];
#pragma unroll
        for (int r = 0; r < 4; r++) {
            int n = row0 + rbase + r;
            if (n < N) {
                float v = acc[t][r] + bias;
                Q[(size_t)n * 800 + h * 78 + c] = __float2half(v > 0.f ? v : expm1f(v));
            }
        }
    }
}

// zero Q pad cols 780..799
__global__ void k_zpadQ(__half2* __restrict__ Q2, int N) {
    int idx = blockIdx.x * 256 + threadIdx.x;
    if (idx >= N * 10) return;
    int n = idx / 10, j = idx - n * 10;
    Q2[(size_t)n * 400 + 390 + j] = __floats2half2_rn(0.f, 0.f);
}

// ---------------- MFMA GEMM2: h216[N][128] = Q[N][800] @ W2T^T ----------------
__global__ __launch_bounds__(256) void k_gemm2(const __half* __restrict__ Q,
                                               const __half* __restrict__ W2T,
                                               __half* __restrict__ h216, int N) {
    int wid = threadIdx.x >> 6, lane = threadIdx.x & 63;
    int row0 = blockIdx.x * 64 + wid * 16;
    int ar = min(row0 + (lane & 15), N - 1);
    int ko = (lane >> 4) * 8;
    f4v acc[8] = {};
    const __half* Aq = Q + (size_t)ar * 800 + ko;
    const __half* Bb = W2T + (size_t)(lane & 15) * 800 + ko;
    for (int ks = 0; ks < 25; ks++) {
        h8v a = *(const h8v*)(Aq + ks * 32);
#pragma unroll
        for (int t = 0; t < 8; t++) {
            h8v b = *(const h8v*)(Bb + (size_t)t * 16 * 800 + ks * 32);
            acc[t] = __builtin_amdgcn_mfma_f32_16x16x32_f16(a, b, acc[t], 0, 0, 0);
        }
    }
    int col16 = lane & 15, rbase = (lane >> 4) * 4;
#pragma unroll
    for (int t = 0; t < 8; t++) {
#pragma unroll
        for (int r = 0; r < 4; r++) {
            int n = row0 + rbase + r;
            if (n < N) h216[(size_t)n * 128 + t * 16 + col16] = __float2half(acc[t][r]);
        }
    }
}

// ---------------- layer-2 coefs from fp16 h2 ----------------
__global__ void k_coef1(const __half2* __restrict__ h216, const float* __restrict__ as2,
                        const float* __restrict__ ad2, float* __restrict__ es,
                        float* __restrict__ ed, int N) {
    int n = blockIdx.x * 256 + threadIdx.x;
    if (n >= N) return;
    const __half2* hp = h216 + (size_t)n * 64;
    float s = 0.f, d = 0.f;
#pragma unroll 8
    for (int j = 0; j < 64; j++) {
        float2 f = __half22float2(hp[j]);
        s = fmaf(f.x, as2[2 * j], s);
        d = fmaf(f.x, ad2[2 * j], d);
        s = fmaf(f.y, as2[2 * j + 1], s);
        d = fmaf(f.y, ad2[2 * j + 1], d);
    }
    es[n] = s;
    ed[n] = d;
}

// ---------------- layer-2 GAT (1 head, 128 ch) + fused relu/max-pool ----------------
__global__ void k_gatP(const int* __restrict__ rp, const int* __restrict__ csrc,
                       const float* __restrict__ es, const float* __restrict__ ed,
                       const __half2* __restrict__ h216, const float* __restrict__ b2,
                       const int* __restrict__ batch, unsigned* __restrict__ gb, int N) {
    int node = blockIdx.x * 4 + (threadIdx.x >> 6);
    if (node >= N) return;
    int lane = threadIdx.x & 63;
    int beg = rp[node], end = rp[node + 1];
    int deg = end - beg;
    float edn = ed[node];

    float acc0 = 0.f, acc1 = 0.f;

    if (deg <= 64) {
        bool act = lane < deg;
        int s = act ? csrc[beg + lane] : 0;
        float v = -3.0e38f;
        if (act) {
            v = es[s] + edn;
            v = v >= 0.f ? v : 0.2f * v;
        }
        float m = v;
        int start = (deg <= 16) ? 8 : 32;
        for (int off = start; off; off >>= 1) m = fmaxf(m, __shfl_xor(m, off));
        float p = act ? __expf(v - m) : 0.f;
        float ss = p;
        for (int off = start; off; off >>= 1) ss += __shfl_xor(ss, off);
        p *= 1.f / ss;

        for (int i = 0; i < deg; i++) {
            int sb = __shfl(s, i);
            float a = __shfl(p, i);
            float2 f = __half22float2(h216[(size_t)sb * 64 + lane]);
            acc0 = fmaf(a, f.x, acc0);
            acc1 = fmaf(a, f.y, acc1);
        }
    } else {
        float m = -3.0e38f, ss = 0.f;
        for (int cb = beg; cb < end; cb += 64) {
            int e = cb + lane;
            bool act = e < end;
            int s = act ? csrc[e] : 0;
            float v = -3.0e38f;
            if (act) {
                v = es[s] + edn;
                v = v >= 0.f ? v : 0.2f * v;
            }
            if (v > m) { ss = ss * __expf(m - v) + 1.f; m = v; }
            else ss += __expf(v - m);
        }
#pragma unroll
        for (int off = 32; off; off >>= 1) {
            float om = __shfl_xor(m, off), os = __shfl_xor(ss, off);
            float nm = fmaxf(m, om);
            ss = ss * __expf(m - nm) + os * __expf(om - nm);
            m = nm;
        }
        float inv = 1.f / ss;
        for (int cb = beg; cb < end; cb += 64) {
            int cnt = min(64, end - cb);
            int e = cb + lane;
            bool act = e < end;
            int s = act ? csrc[e] : 0;
            float p = 0.f;
            if (act) {
                float v = es[s] + edn;
                v = v >= 0.f ? v : 0.2f * v;
                p = __expf(v - m) * inv;
            }
            for (int i = 0; i < cnt; i++) {
                int sb = __shfl(s, i);
                float a = __shfl(p, i);
                float2 f = __half22float2(h216[(size_t)sb * 64 + lane]);
                acc0 = fmaf(a, f.x, acc0);
                acc1 = fmaf(a, f.y, acc1);
            }
        }
    }

    unsigned* gp = gb + (size_t)batch[node] * F2;
    float t0 = fmaxf(acc0 + b2[2 * lane], 0.f);
    atomicMax(&gp[2 * lane], __float_as_uint(t0));
    float t1 = fmaxf(acc1 + b2[2 * lane + 1], 0.f);
    atomicMax(&gp[2 * lane + 1], __float_as_uint(t1));
}

// ---------------- head ----------------
__global__ void k_head_g(const unsigned* __restrict__ gbits, const float* __restrict__ Wg,
                         const float* __restrict__ bg, float* __restrict__ xc) {
    int b = blockIdx.x, c = threadIdx.x;
    __shared__ float srow[F2];
    srow[c] = __uint_as_float(gbits[(size_t)b * F2 + c]);
    __syncthreads();
    float acc = bg[c];
    for (int k = 0; k < F2; k++) acc = fmaf(srow[k], Wg[k * F2 + c], acc);
    xc[(size_t)b * 256 + c] = fmaxf(acc, 0.f);
}

__global__ void k_head_xt(const float* __restrict__ te, const float* __restrict__ Wxt,
                          const float* __restrict__ bxt, const float* __restrict__ gamma,
                          const float* __restrict__ beta, const float* __restrict__ rmean,
                          const float* __restrict__ rvar, float* __restrict__ xc) {
    int b = blockIdx.x, c = threadIdx.x;
    __shared__ float srow[EMB];
    for (int k = c; k < EMB; k += 128) srow[k] = te[(size_t)b * EMB + k];
    __syncthreads();
    float acc = bxt[c];
    for (int k = 0; k < EMB; k++) acc = fmaf(srow[k], Wxt[k * F2 + c], acc);
    acc = (acc - rmean[c]) * rsqrtf(rvar[c] + 1e-5f) * gamma[c] + beta[c];
    xc[(size_t)b * 256 + 128 + c] = fmaxf(acc, 0.f);
}

__global__ void k_head_f1(const float* __restrict__ xc, const float* __restrict__ W,
                          const float* __restrict__ bias, float* __restrict__ o) {
    int b = blockIdx.x;
    __shared__ float srow[256];
    srow[threadIdx.x] = xc[(size_t)b * 256 + threadIdx.x];
    __syncthreads();
    for (int col = threadIdx.x; col < 1024; col += 256) {
        float acc = bias[col];
        for (int k = 0; k < 256; k++) acc = fmaf(srow[k], W[k * 1024 + col], acc);
        o[(size_t)b * 1024 + col] = fmaxf(acc, 0.f);
    }
}

__global__ void k_head_f2(const float* __restrict__ in, const float* __restrict__ W,
                          const float* __restrict__ bias, float* __restrict__ o) {
    int b = blockIdx.x;
    int col = threadIdx.x;
    __shared__ float srow[1024];
    for (int k = col; k < 1024; k += 256) srow[k] = in[(size_t)b * 1024 + k];
    __syncthreads();
    float acc = bias[col];
    for (int k = 0; k < 1024; k++) acc = fmaf(srow[k], W[k * 256 + col], acc);
    o[(size_t)b * 256 + col] = fmaxf(acc, 0.f);
}

__global__ void k_head_out(const float* __restrict__ in, const float* __restrict__ Wo,
                           const float* __restrict__ bo, float* __restrict__ out) {
    int b = blockIdx.x;
    float acc = 0.f;
    for (int k = threadIdx.x; k < 256; k += 64) acc = fmaf(in[(size_t)b * 256 + k], Wo[k], acc);
    for (int off = 32; off; off >>= 1) acc += __shfl_down(acc, off);
    if (threadIdx.x == 0) out[b] = acc + bo[0];
}

extern "C" void kernel_launch(void* const* d_in, const int* in_sizes, int n_in,
                              void* d_out, int out_size, void* d_ws, size_t ws_size,
                              hipStream_t stream) {
    const float* x     = (const float*)d_in[0];
    const int*   ei    = (const int*)d_in[1];
    const int*   batch = (const int*)d_in[2];
    const float* te    = (const float*)d_in[3];
    const float* W1    = (const float*)d_in[4];
    const float* a1s   = (const float*)d_in[5];
    const float* a1d   = (const float*)d_in[6];
    const float* b1    = (const float*)d_in[7];
    const float* W2    = (const float*)d_in[8];
    const float* a2s   = (const float*)d_in[9];
    const float* a2d   = (const float*)d_in[10];
    const float* b2    = (const float*)d_in[11];
    const float* Wg    = (const float*)d_in[12];
    const float* bg    = (const float*)d_in[13];
    const float* Wxt   = (const float*)d_in[14];
    const float* bxt   = (const float*)d_in[15];
    const float* gamma = (const float*)d_in[16];
    const float* beta  = (const float*)d_in[17];
    const float* rmean = (const float*)d_in[18];
    const float* rvar  = (const float*)d_in[19];
    const float* Wf1   = (const float*)d_in[20];
    const float* bf1   = (const float*)d_in[21];
    const float* Wf2   = (const float*)d_in[22];
    const float* bf2   = (const float*)d_in[23];
    const float* Wo    = (const float*)d_in[24];
    const float* bo    = (const float*)d_in[25];

    const int N = in_sizes[0] / 78;
    const int E = in_sizes[1] / 2;
    const int B = in_sizes[3] / EMB;
    const int Etot = E + N;
    const int* src = ei;
    const int* dst = ei + E;

    char* p = (char*)d_ws;
    auto alloc = [&](size_t bytes) -> void* {
        void* r = p;
        p += (bytes + 255) & ~(size_t)255;
        return r;
    };
    __half*   x16  = (__half*)alloc((size_t)N * 96 * 2);    // 9.6 MB
    __half*   xagg = (__half*)alloc((size_t)N * 480 * 2);   // 48 MB
    __half*   Q16  = (__half*)alloc((size_t)N * 800 * 2);   // 80 MB
    __half*   h216 = (__half*)alloc((size_t)N * 128 * 2);   // 12.8 MB
    float*    esg  = (float*)alloc((size_t)2 * N * 8 * 4);  // 3.2 MB
    float*    edg  = (float*)alloc((size_t)2 * N * 8 * 4);  // 3.2 MB
    float*    es2  = (float*)alloc((size_t)N * 4);
    float*    ed2  = (float*)alloc((size_t)N * 4);
    __half*   W1T  = (__half*)alloc((size_t)10 * 80 * 96 * 2);
    __half*   W2T  = (__half*)alloc((size_t)128 * 800 * 2);
    float*    wes  = (float*)alloc((size_t)800 * 4);
    float*    wed  = (float*)alloc((size_t)800 * 4);
    int*      cnt  = (int*)alloc((size_t)N * 4);
    int*      rp   = (int*)alloc((size_t)(N + 1) * 4);
    int*      cur  = (int*)alloc((size_t)N * 4);
    int*      csrc = (int*)alloc((size_t)Etot * 4);
    int*      bsum = (int*)alloc((size_t)1024 * 4);
    unsigned* gb   = (unsigned*)alloc((size_t)B * F2 * 4);
    float*    xc   = (float*)alloc((size_t)B * 256 * 4);
    float*    f1o  = (float*)alloc((size_t)B * 1024 * 4);
    float*    f2o  = (float*)alloc((size_t)B * 256 * 4);

    auto gsz = [](long long t) { return (int)((t + 255) / 256); };
    const int nb = gsz(N);
    const int nwave = (N + 3) / 4;
    const int nrow64 = (N + 63) / 64;

    // ---- CSR build ----
    hipMemsetAsync(cnt, 0, (size_t)N * 4, stream);
    k_count<<<gsz(Etot), 256, 0, stream>>>(src, dst, E, Etot, cnt);
    k_scan1<<<nb, 256, 0, stream>>>(cnt, rp, bsum, N);
    k_scan2<<<1, 256, 0, stream>>>(bsum, nb);
    k_scan3<<<nb, 256, 0, stream>>>(rp, bsum, N, Etot, rp + N);
    hipMemcpyAsync(cur, rp, (size_t)N * 4, hipMemcpyDeviceToDevice, stream);
    k_scatter<<<gsz(Etot), 256, 0, stream>>>(src, dst, E, Etot, cur, csrc);

    // ---- prep ----
    k_prep_w1t<<<gsz(10 * 80 * 96), 256, 0, stream>>>(W1, W1T);
    k_prep_wes<<<gsz(800), 256, 0, stream>>>(W1, a1s, a1d, wes, wed);
    k_prep_w2t<<<gsz(128 * 800), 256, 0, stream>>>(W2, W2T);
    k_prep_x16<<<gsz((long long)N * 96), 256, 0, stream>>>(x, x16, N);
    k_coefx<<<nb, 256, 0, stream>>>(x, wes, wed, esg, edg, N);

    hipMemsetAsync(gb, 0, (size_t)B * F2 * 4, stream);

    // ---- GAT layer 1: 2 groups of 5 heads (aggregate x, then per-head MFMA GEMM) ----
    for (int g = 0; g < 2; g++) {
        k_gatx5<<<nwave, 256, 0, stream>>>(rp, csrc, esg + (size_t)g * N * 8,
                                           edg + (size_t)g * N * 8, x16, xagg, N);
        k_gemm_hh<<<dim3(nrow64, 5), 256, 0, stream>>>(xagg, W1T, b1, Q16, g, N);
    }
    k_zpadQ<<<gsz((long long)N * 10), 256, 0, stream>>>((__half2*)Q16, N);

    // ---- GEMM2 (MFMA) -> h2 (fp16) ----
    k_gemm2<<<nrow64, 256, 0, stream>>>(Q16, W2T, h216, N);

    // ---- GAT layer 2 (1 head, 128 ch) + fused pool ----
    k_coef1<<<nb, 256, 0, stream>>>((const __half2*)h216, a2s, a2d, es2, ed2, N);
    k_gatP<<<nwave, 256, 0, stream>>>(rp, csrc, es2, ed2, (const __half2*)h216, b2, batch, gb, N);

    // ---- head ----
    k_head_g<<<B, 128, 0, stream>>>(gb, Wg, bg, xc);
    k_head_xt<<<B, 128, 0, stream>>>(te, Wxt, bxt, gamma, beta, rmean, rvar, xc);
    k_head_f1<<<B, 256, 0, stream>>>(xc, Wf1, bf1, f1o);
    k_head_f2<<<B, 256, 0, stream>>>(f1o, Wf2, bf2, f2o);
    k_head_out<<<B, 64, 0, stream>>>(f2o, Wo, bo, (float*)d_out);
}